// Round 1
// baseline (515.048 us; speedup 1.0000x reference)
//
#include <hip/hip_runtime.h>
#include <cstdint>
#include <cstddef>

typedef unsigned short u16;
typedef __attribute__((ext_vector_type(8))) short bf16x8;
typedef __attribute__((ext_vector_type(4))) float f32x4;

#define AS1 __attribute__((address_space(1)))
#define AS3 __attribute__((address_space(3)))
#define GLDS16(g, s) __builtin_amdgcn_global_load_lds((const AS1 void*)(g), (AS3 void*)(s), 16, 0, 0)

__device__ inline u16 f2bf(float f) {
  union { float f; unsigned u; } c; c.f = f;
  unsigned r = c.u + 0x7fffu + ((c.u >> 16) & 1u);
  return (u16)(r >> 16);
}
__device__ inline float bf2f(u16 s) {
  union { unsigned u; float f; } c; c.u = ((unsigned)s) << 16;
  return c.f;
}

// ---------------- weight f32 (K,N) -> bf16 (N,K) ----------------
__global__ __launch_bounds__(256)
void wconv_t(const float* __restrict__ W, u16* __restrict__ Wt, int K, int N) {
  __shared__ float tile[32][33];
  const int tx = threadIdx.x, ty = threadIdx.y;
  const int n0 = blockIdx.x * 32, k0 = blockIdx.y * 32;
#pragma unroll
  for (int i = 0; i < 4; ++i)
    tile[ty + i * 8][tx] = W[(size_t)(k0 + ty + i * 8) * N + n0 + tx];
  __syncthreads();
#pragma unroll
  for (int i = 0; i < 4; ++i)
    Wt[(size_t)(n0 + ty + i * 8) * K + k0 + tx] = f2bf(tile[tx][ty + i * 8]);
}

// ---------------- modulation ----------------
__global__ __launch_bounds__(256)
void silu_kernel(const float* __restrict__ vec, float* __restrict__ sv) {
  int i = blockIdx.x * 256 + threadIdx.x;
  float x = vec[i];
  sv[i] = x / (1.f + __expf(-x));
}

__global__ __launch_bounds__(256)
void modinit(const float* __restrict__ imb, const float* __restrict__ tmb, float* __restrict__ mod) {
  int i = blockIdx.x * 256 + threadIdx.x;  // 8192
  mod[i] = (i < 6144) ? imb[i] : tmb[i - 6144];
}

__global__ __launch_bounds__(256)
void modgemv(const float* __restrict__ sv, const float* __restrict__ imw,
             const float* __restrict__ tmw, float* __restrict__ mod) {
  __shared__ float s[128];
  const int t = threadIdx.x;
  const int c = blockIdx.x * 256 + t;       // 0..8191
  const int kc = blockIdx.y * 128;          // k chunk
  if (t < 128) s[t] = sv[kc + t];
  __syncthreads();
  const float* W; int col;
  if (c < 6144) { W = imw; col = c; } else { W = tmw; col = c - 6144; }
  float acc = 0.f;
#pragma unroll 8
  for (int k = 0; k < 128; ++k) acc += s[k] * W[(size_t)(kc + k) * 6144 + col];
  atomicAdd(&mod[c], acc);
}

// ---------------- LayerNorm + modulate -> bf16 ----------------
__global__ __launch_bounds__(256)
void ln_mod(const float* __restrict__ x, const float* __restrict__ shift,
            const float* __restrict__ scale, u16* __restrict__ out) {
  const int row = blockIdx.x, t = threadIdx.x;
  const float* xr = x + (size_t)row * 1024;
  float v[4], s = 0.f, sq = 0.f;
#pragma unroll
  for (int i = 0; i < 4; ++i) { v[i] = xr[t + i * 256]; s += v[i]; sq += v[i] * v[i]; }
#pragma unroll
  for (int o = 32; o; o >>= 1) { s += __shfl_down(s, o); sq += __shfl_down(sq, o); }
  __shared__ float ls[8];
  if ((t & 63) == 0) { ls[t >> 6] = s; ls[4 + (t >> 6)] = sq; }
  __syncthreads();
  s = ls[0] + ls[1] + ls[2] + ls[3];
  sq = ls[4] + ls[5] + ls[6] + ls[7];
  const float mean = s * (1.f / 1024.f);
  const float var = sq * (1.f / 1024.f) - mean * mean;
  const float rstd = rsqrtf(var + 1e-6f);
#pragma unroll
  for (int i = 0; i < 4; ++i) {
    int c = t + i * 256;
    float xn = (v[i] - mean) * rstd;
    out[(size_t)row * 1024 + c] = f2bf((1.f + scale[c]) * xn + shift[c]);
  }
}

// ---------------- GEMM: C = A(MxK) * Bt(NxK)^T, bf16 in, fused epilogues ----------------
// EPI 0: bf16 out = acc + bias ; EPI 2: bf16 out = gelu(acc+bias)
// EPI 1/3: f32 out = resid + gate[col]*(acc+bias)
template <int EPI>
__global__ __launch_bounds__(256, 2)
void gemm_bt(const u16* __restrict__ A, const u16* __restrict__ Bt,
             int M, int N, int K,
             const float* __restrict__ bias, const float* __restrict__ gate,
             const float* __restrict__ resid, void* __restrict__ Cout) {
  __shared__ u16 smA[128 * 32];
  __shared__ u16 smB[128 * 32];
  const int t = threadIdx.x;
  const int w = t >> 6, l = t & 63;
  const int lr = l & 15, lg = l >> 4;
  const int m0 = blockIdx.x * 128, n0 = blockIdx.y * 128;
  const int wm = (w >> 1) * 64, wn = (w & 1) * 64;
  f32x4 acc[4][4] = {};
  const int c0 = w * 64 + l, c1 = c0 + 256;
  const int r0 = c0 >> 2, cb0 = (c0 & 3) << 3;
  const int r1 = c1 >> 2, cb1 = (c1 & 3) << 3;
  const int nk = K >> 5;
  for (int kt = 0; kt < nk; ++kt) {
    const int k0 = kt << 5;
    GLDS16(A + (size_t)(m0 + r0) * K + k0 + cb0, smA + (w * 64) * 8);
    GLDS16(A + (size_t)(m0 + r1) * K + k0 + cb1, smA + (256 + w * 64) * 8);
    GLDS16(Bt + (size_t)(n0 + r0) * K + k0 + cb0, smB + (w * 64) * 8);
    GLDS16(Bt + (size_t)(n0 + r1) * K + k0 + cb1, smB + (256 + w * 64) * 8);
    __syncthreads();
    bf16x8 af[4], bfr[4];
#pragma unroll
    for (int m = 0; m < 4; ++m)
      af[m] = *(const bf16x8*)(smA + (wm + m * 16 + lr) * 32 + lg * 8);
#pragma unroll
    for (int n = 0; n < 4; ++n)
      bfr[n] = *(const bf16x8*)(smB + (wn + n * 16 + lr) * 32 + lg * 8);
#pragma unroll
    for (int m = 0; m < 4; ++m)
#pragma unroll
      for (int n = 0; n < 4; ++n)
        acc[m][n] = __builtin_amdgcn_mfma_f32_16x16x32_bf16(af[m], bfr[n], acc[m][n], 0, 0, 0);
    __syncthreads();
  }
#pragma unroll
  for (int m = 0; m < 4; ++m) {
    const int row = m0 + wm + m * 16 + lg * 4;
#pragma unroll
    for (int n = 0; n < 4; ++n) {
      const int col = n0 + wn + n * 16 + lr;
#pragma unroll
      for (int i = 0; i < 4; ++i) {
        float v = acc[m][n][i];
        size_t idx = (size_t)(row + i) * N + col;
        if constexpr (EPI == 0) {
          ((u16*)Cout)[idx] = f2bf(v + bias[col]);
        } else if constexpr (EPI == 2) {
          float cc = v + bias[col];
          float u = 0.7978845608f * (cc + 0.044715f * cc * cc * cc);
          float e = __expf(2.f * u);
          float th = 1.f - 2.f / (e + 1.f);
          ((u16*)Cout)[idx] = f2bf(0.5f * cc * (1.f + th));
        } else {
          ((float*)Cout)[idx] = resid[idx] + gate[col] * (v + bias[col]);
        }
      }
    }
  }
}

// ---------------- q/k: RMS norm + RoPE -> Q,K (h,pos,d) bf16 ----------------
__global__ __launch_bounds__(256)
void qk_post(const u16* __restrict__ qkv_txt, const u16* __restrict__ qkv_img,
             const float* __restrict__ pe,
             const float* __restrict__ iq_s, const float* __restrict__ ik_s,
             const float* __restrict__ tq_s, const float* __restrict__ tk_s,
             u16* __restrict__ Q, u16* __restrict__ K) {
  const int d = threadIdx.x;                       // 0..63
  const int pos = blockIdx.x * 4 + threadIdx.y;    // 0..2303
  const int h = blockIdx.y;
  const u16* src; int r; const float *qs, *ks;
  if (pos < 256) { src = qkv_txt; r = pos; qs = tq_s; ks = tk_s; }
  else           { src = qkv_img; r = pos - 256; qs = iq_s; ks = ik_s; }
  float q = bf2f(src[(size_t)r * 3072 + h * 64 + d]);
  float k = bf2f(src[(size_t)r * 3072 + 1024 + h * 64 + d]);
  float qsq = q * q, ksq = k * k;
#pragma unroll
  for (int o = 32; o; o >>= 1) { qsq += __shfl_xor(qsq, o); ksq += __shfl_xor(ksq, o); }
  q *= rsqrtf(qsq * (1.f / 64.f) + 1e-6f) * qs[d];
  k *= rsqrtf(ksq * (1.f / 64.f) + 1e-6f) * ks[d];
  const int p = d >> 1, odd = d & 1;
  const float* pp = pe + (((size_t)pos * 32 + p) * 2 + odd) * 2;
  float qp = __shfl_xor(q, 1), kp = __shfl_xor(k, 1);
  float qe = odd ? qp : q, qo = odd ? q : qp;
  float ke = odd ? kp : k, ko = odd ? k : kp;
  float rq = pp[0] * qe + pp[1] * qo;
  float rk = pp[0] * ke + pp[1] * ko;
  size_t oidx = ((size_t)h * 2304 + pos) * 64 + d;
  Q[oidx] = f2bf(rq);
  K[oidx] = f2bf(rk);
}

// ---------------- V -> Vt (h, d, pos) bf16 ----------------
__global__ __launch_bounds__(512)
void v_transpose(const u16* __restrict__ qkv_txt, const u16* __restrict__ qkv_img,
                 u16* __restrict__ Vt) {
  __shared__ float tile[64][65];
  const int tx = threadIdx.x, ty = threadIdx.y;   // 64 x 8
  const int p0 = blockIdx.x * 64, h = blockIdx.y;
#pragma unroll
  for (int i = 0; i < 8; ++i) {
    int pos = p0 + ty + i * 8;
    const u16* src; int r;
    if (pos < 256) { src = qkv_txt; r = pos; } else { src = qkv_img; r = pos - 256; }
    tile[ty + i * 8][tx] = bf2f(src[(size_t)r * 3072 + 2048 + h * 64 + tx]);
  }
  __syncthreads();
#pragma unroll
  for (int i = 0; i < 8; ++i) {
    int d = ty + i * 8;
    Vt[((size_t)h * 64 + d) * 2304 + p0 + tx] = f2bf(tile[tx][d]);
  }
}

// ---------------- flash attention: Q(h,pos,d) K(h,pos,d) Vt(h,d,pos) -> out (pos, h*64+d) bf16 ----------------
__global__ __launch_bounds__(256, 2)
void attn_kernel(const u16* __restrict__ Q, const u16* __restrict__ Kb,
                 const u16* __restrict__ Vt, u16* __restrict__ outb) {
  __shared__ u16 smK[64 * 64];
  __shared__ u16 smV[64 * 64];
  __shared__ u16 smP[4 * 16 * 72];
  const int t = threadIdx.x, w = t >> 6, l = t & 63;
  const int lr = l & 15, lg = l >> 4;
  const int qt = blockIdx.x, h = blockIdx.y;
  const u16* Qp = Q + ((size_t)h * 2304 + qt * 64 + w * 16 + lr) * 64;
  const bf16x8 qf0 = *(const bf16x8*)(Qp + lg * 8);
  const bf16x8 qf1 = *(const bf16x8*)(Qp + 32 + lg * 8);
  const u16* Kbase = Kb + (size_t)h * 2304 * 64;
  const u16* Vbase = Vt + (size_t)h * 64 * 2304;
  f32x4 accO[4] = {};
  float mrow[4] = {-1e30f, -1e30f, -1e30f, -1e30f};
  float lrow[4] = {};
  u16* myP = smP + w * (16 * 72);
  for (int j = 0; j < 36; ++j) {
    {
      const u16* g = Kbase + (size_t)j * 64 * 64;
      GLDS16(g + (size_t)(w * 64 + l) * 8, smK + (w * 64) * 8);
      GLDS16(g + (size_t)(256 + w * 64 + l) * 8, smK + (256 + w * 64) * 8);
      const int c0 = w * 64 + l, c1 = c0 + 256;
      GLDS16(Vbase + (size_t)(c0 >> 3) * 2304 + j * 64 + (c0 & 7) * 8, smV + (w * 64) * 8);
      GLDS16(Vbase + (size_t)(c1 >> 3) * 2304 + j * 64 + (c1 & 7) * 8, smV + (256 + w * 64) * 8);
    }
    __syncthreads();
    f32x4 sf[4];
#pragma unroll
    for (int n = 0; n < 4; ++n) {
      bf16x8 kf0 = *(const bf16x8*)(smK + (n * 16 + lr) * 64 + lg * 8);
      bf16x8 kf1 = *(const bf16x8*)(smK + (n * 16 + lr) * 64 + 32 + lg * 8);
      f32x4 z = {};
      z = __builtin_amdgcn_mfma_f32_16x16x32_bf16(qf0, kf0, z, 0, 0, 0);
      z = __builtin_amdgcn_mfma_f32_16x16x32_bf16(qf1, kf1, z, 0, 0, 0);
      sf[n] = z * 0.125f;
    }
    float corr[4];
#pragma unroll
    for (int i = 0; i < 4; ++i) {
      float mx = fmaxf(fmaxf(sf[0][i], sf[1][i]), fmaxf(sf[2][i], sf[3][i]));
#pragma unroll
      for (int o = 1; o < 16; o <<= 1) mx = fmaxf(mx, __shfl_xor(mx, o));
      float mnew = fmaxf(mrow[i], mx);
      corr[i] = __expf(mrow[i] - mnew);
      float rs = 0.f;
#pragma unroll
      for (int n = 0; n < 4; ++n) {
        float p = __expf(sf[n][i] - mnew);
        sf[n][i] = p;
        rs += p;
      }
#pragma unroll
      for (int o = 1; o < 16; o <<= 1) rs += __shfl_xor(rs, o);
      lrow[i] = lrow[i] * corr[i] + rs;
      mrow[i] = mnew;
    }
#pragma unroll
    for (int n = 0; n < 4; ++n)
#pragma unroll
      for (int i = 0; i < 4; ++i) {
        accO[n][i] *= corr[i];
        myP[(lg * 4 + i) * 72 + n * 16 + lr] = f2bf(sf[n][i]);
      }
#pragma unroll
    for (int c = 0; c < 2; ++c) {
      bf16x8 pf = *(const bf16x8*)(myP + lr * 72 + c * 32 + lg * 8);
#pragma unroll
      for (int nd = 0; nd < 4; ++nd) {
        bf16x8 vf = *(const bf16x8*)(smV + (nd * 16 + lr) * 64 + c * 32 + lg * 8);
        accO[nd] = __builtin_amdgcn_mfma_f32_16x16x32_bf16(pf, vf, accO[nd], 0, 0, 0);
      }
    }
    __syncthreads();
  }
#pragma unroll
  for (int nd = 0; nd < 4; ++nd) {
    const int col = h * 64 + nd * 16 + lr;
#pragma unroll
    for (int i = 0; i < 4; ++i) {
      int row = qt * 64 + w * 16 + lg * 4 + i;
      outb[(size_t)row * 1024 + col] = f2bf(accO[nd][i] / lrow[i]);
    }
  }
}

// ---------------- host ----------------
extern "C" void kernel_launch(void* const* d_in, const int* in_sizes, int n_in,
                              void* d_out, int out_size, void* d_ws, size_t ws_size,
                              hipStream_t stream) {
  const float* img         = (const float*)d_in[0];
  const float* txt         = (const float*)d_in[1];
  const float* pe          = (const float*)d_in[2];
  const float* vec         = (const float*)d_in[3];
  const float* img_mod_w   = (const float*)d_in[4];
  const float* img_mod_b   = (const float*)d_in[5];
  const float* txt_mod_w   = (const float*)d_in[6];
  const float* txt_mod_b   = (const float*)d_in[7];
  const float* img_qkv_w   = (const float*)d_in[8];
  const float* img_qkv_b   = (const float*)d_in[9];
  const float* img_q_scale = (const float*)d_in[10];
  const float* img_k_scale = (const float*)d_in[11];
  const float* img_proj_w  = (const float*)d_in[12];
  const float* img_proj_b  = (const float*)d_in[13];
  const float* txt_qkv_w   = (const float*)d_in[14];
  const float* txt_qkv_b   = (const float*)d_in[15];
  const float* txt_q_scale = (const float*)d_in[16];
  const float* txt_k_scale = (const float*)d_in[17];
  const float* mlp_w1      = (const float*)d_in[18];
  const float* mlp_b1      = (const float*)d_in[19];
  const float* mlp_w2      = (const float*)d_in[20];
  const float* mlp_b2      = (const float*)d_in[21];
  (void)in_sizes; (void)n_in; (void)out_size; (void)ws_size;

  char* ws = (char*)d_ws;
  size_t off = 0;
  auto alloc = [&](size_t bytes) -> void* {
    void* p = ws + off;
    off += (bytes + 255) & ~(size_t)255;
    return p;
  };
  float* sv     = (float*)alloc(1024 * 4);
  float* mod    = (float*)alloc(8192 * 4);
  u16* img_m    = (u16*)alloc((size_t)2048 * 1024 * 2);
  u16* txt_m    = (u16*)alloc((size_t)256 * 1024 * 2);
  u16* wt_iqkv  = (u16*)alloc((size_t)3072 * 1024 * 2);
  u16* wt_tqkv  = (u16*)alloc((size_t)3072 * 1024 * 2);
  u16* wt_proj  = (u16*)alloc((size_t)1024 * 1024 * 2);
  u16* wt_m1    = (u16*)alloc((size_t)4096 * 1024 * 2);
  u16* wt_m2    = (u16*)alloc((size_t)1024 * 4096 * 2);
  u16* qkv_img  = (u16*)alloc((size_t)2048 * 3072 * 2);
  u16* qkv_txt  = (u16*)alloc((size_t)256 * 3072 * 2);
  u16* Qb       = (u16*)alloc((size_t)16 * 2304 * 64 * 2);
  u16* Kb       = (u16*)alloc((size_t)16 * 2304 * 64 * 2);
  u16* Vtb      = (u16*)alloc((size_t)16 * 64 * 2304 * 2);
  u16* attnb    = (u16*)alloc((size_t)2304 * 1024 * 2);
  float* img2   = (float*)alloc((size_t)2048 * 1024 * 4);
  u16* h_in     = (u16*)alloc((size_t)2048 * 1024 * 2);
  u16* h1       = (u16*)alloc((size_t)2048 * 4096 * 2);

  const dim3 bT(32, 8);
  wconv_t<<<dim3(3072 / 32, 1024 / 32), bT, 0, stream>>>(img_qkv_w, wt_iqkv, 1024, 3072);
  wconv_t<<<dim3(3072 / 32, 1024 / 32), bT, 0, stream>>>(txt_qkv_w, wt_tqkv, 1024, 3072);
  wconv_t<<<dim3(1024 / 32, 1024 / 32), bT, 0, stream>>>(img_proj_w, wt_proj, 1024, 1024);
  wconv_t<<<dim3(4096 / 32, 1024 / 32), bT, 0, stream>>>(mlp_w1, wt_m1, 1024, 4096);
  wconv_t<<<dim3(1024 / 32, 4096 / 32), bT, 0, stream>>>(mlp_w2, wt_m2, 4096, 1024);

  silu_kernel<<<4, 256, 0, stream>>>(vec, sv);
  modinit<<<32, 256, 0, stream>>>(img_mod_b, txt_mod_b, mod);
  modgemv<<<dim3(32, 8), 256, 0, stream>>>(sv, img_mod_w, txt_mod_w, mod);

  ln_mod<<<2048, 256, 0, stream>>>(img, mod + 0, mod + 1024, img_m);
  ln_mod<<<256, 256, 0, stream>>>(txt, mod + 6144, mod + 7168, txt_m);

  gemm_bt<0><<<dim3(16, 24), 256, 0, stream>>>(img_m, wt_iqkv, 2048, 3072, 1024,
                                               img_qkv_b, nullptr, nullptr, qkv_img);
  gemm_bt<0><<<dim3(2, 24), 256, 0, stream>>>(txt_m, wt_tqkv, 256, 3072, 1024,
                                              txt_qkv_b, nullptr, nullptr, qkv_txt);

  qk_post<<<dim3(576, 16), dim3(64, 4), 0, stream>>>(qkv_txt, qkv_img, pe,
                                                     img_q_scale, img_k_scale,
                                                     txt_q_scale, txt_k_scale, Qb, Kb);
  v_transpose<<<dim3(36, 16), dim3(64, 8), 0, stream>>>(qkv_txt, qkv_img, Vtb);

  attn_kernel<<<dim3(36, 16), 256, 0, stream>>>(Qb, Kb, Vtb, attnb);

  gemm_bt<1><<<dim3(16, 8), 256, 0, stream>>>(attnb + (size_t)256 * 1024, wt_proj,
                                              2048, 1024, 1024,
                                              img_proj_b, mod + 2048, img, img2);
  ln_mod<<<2048, 256, 0, stream>>>(img2, mod + 3072, mod + 4096, h_in);
  gemm_bt<2><<<dim3(16, 32), 256, 0, stream>>>(h_in, wt_m1, 2048, 4096, 1024,
                                               mlp_b1, nullptr, nullptr, h1);
  gemm_bt<3><<<dim3(16, 8), 256, 0, stream>>>(h1, wt_m2, 2048, 1024, 4096,
                                              mlp_b2, mod + 5120, img2, (float*)d_out);
}

// Round 3
// 472.194 us; speedup vs baseline: 1.0908x; 1.0908x over previous
//
#include <hip/hip_runtime.h>
#include <cstdint>
#include <cstddef>

typedef unsigned short u16;
typedef __attribute__((ext_vector_type(8))) short bf16x8;
typedef __attribute__((ext_vector_type(4))) float f32x4;

#define AS1 __attribute__((address_space(1)))
#define AS3 __attribute__((address_space(3)))
#define GLDS16(g, s) __builtin_amdgcn_global_load_lds((const AS1 void*)(g), (AS3 void*)(s), 16, 0, 0)

__device__ inline u16 f2bf(float f) {
  union { float f; unsigned u; } c; c.f = f;
  unsigned r = c.u + 0x7fffu + ((c.u >> 16) & 1u);
  return (u16)(r >> 16);
}
__device__ inline float bf2f(u16 s) {
  union { unsigned u; float f; } c; c.u = ((unsigned)s) << 16;
  return c.f;
}

// ---------------- weight f32 (K,N) -> bf16 (N,K) ----------------
__global__ __launch_bounds__(256)
void wconv_t(const float* __restrict__ W, u16* __restrict__ Wt, int K, int N) {
  __shared__ float tile[32][33];
  const int tx = threadIdx.x, ty = threadIdx.y;
  const int n0 = blockIdx.x * 32, k0 = blockIdx.y * 32;
#pragma unroll
  for (int i = 0; i < 4; ++i)
    tile[ty + i * 8][tx] = W[(size_t)(k0 + ty + i * 8) * N + n0 + tx];
  __syncthreads();
#pragma unroll
  for (int i = 0; i < 4; ++i)
    Wt[(size_t)(n0 + ty + i * 8) * K + k0 + tx] = f2bf(tile[tx][ty + i * 8]);
}

// ---------------- modulation ----------------
__global__ __launch_bounds__(256)
void silu_kernel(const float* __restrict__ vec, float* __restrict__ sv) {
  int i = blockIdx.x * 256 + threadIdx.x;
  float x = vec[i];
  sv[i] = x / (1.f + __expf(-x));
}

__global__ __launch_bounds__(256)
void modinit(const float* __restrict__ imb, const float* __restrict__ tmb, float* __restrict__ mod) {
  int i = blockIdx.x * 256 + threadIdx.x;  // 8192
  mod[i] = (i < 6144) ? imb[i] : tmb[i - 6144];
}

__global__ __launch_bounds__(256)
void modgemv(const float* __restrict__ sv, const float* __restrict__ imw,
             const float* __restrict__ tmw, float* __restrict__ mod) {
  __shared__ float s[128];
  const int t = threadIdx.x;
  const int c = blockIdx.x * 256 + t;       // 0..8191
  const int kc = blockIdx.y * 128;          // k chunk
  if (t < 128) s[t] = sv[kc + t];
  __syncthreads();
  const float* W; int col;
  if (c < 6144) { W = imw; col = c; } else { W = tmw; col = c - 6144; }
  float acc = 0.f;
#pragma unroll 8
  for (int k = 0; k < 128; ++k) acc += s[k] * W[(size_t)(kc + k) * 6144 + col];
  atomicAdd(&mod[c], acc);
}

// ---------------- LayerNorm + modulate -> bf16 ----------------
__global__ __launch_bounds__(256)
void ln_mod(const float* __restrict__ x, const float* __restrict__ shift,
            const float* __restrict__ scale, u16* __restrict__ out) {
  const int row = blockIdx.x, t = threadIdx.x;
  const float* xr = x + (size_t)row * 1024;
  float v[4], s = 0.f, sq = 0.f;
#pragma unroll
  for (int i = 0; i < 4; ++i) { v[i] = xr[t + i * 256]; s += v[i]; sq += v[i] * v[i]; }
#pragma unroll
  for (int o = 32; o; o >>= 1) { s += __shfl_down(s, o); sq += __shfl_down(sq, o); }
  __shared__ float ls[8];
  if ((t & 63) == 0) { ls[t >> 6] = s; ls[4 + (t >> 6)] = sq; }
  __syncthreads();
  s = ls[0] + ls[1] + ls[2] + ls[3];
  sq = ls[4] + ls[5] + ls[6] + ls[7];
  const float mean = s * (1.f / 1024.f);
  const float var = sq * (1.f / 1024.f) - mean * mean;
  const float rstd = rsqrtf(var + 1e-6f);
#pragma unroll
  for (int i = 0; i < 4; ++i) {
    int c = t + i * 256;
    float xn = (v[i] - mean) * rstd;
    out[(size_t)row * 1024 + c] = f2bf((1.f + scale[c]) * xn + shift[c]);
  }
}

// ---------------- GEMM: C = A(MxK) * Bt(NxK)^T, bf16 in, fused epilogues ----------------
// EPI 0: bf16 out = acc + bias ; EPI 2: bf16 out = gelu(acc+bias)
// EPI 1/3: f32 out = resid + gate[col]*(acc+bias)
template <int EPI, int BN>
__global__ __launch_bounds__(256, 3)
void gemm_bt(const u16* __restrict__ A, const u16* __restrict__ Bt,
             int M, int N, int K,
             const float* __restrict__ bias, const float* __restrict__ gate,
             const float* __restrict__ resid, void* __restrict__ Cout) {
  constexpr int NF = BN / 32;               // n-fragments per wave
  __shared__ u16 smA[128 * 32];
  __shared__ u16 smB[BN * 32];
  const int t = threadIdx.x;
  const int w = t >> 6, l = t & 63;
  const int lr = l & 15, lg = l >> 4;
  const int m0 = blockIdx.x * 128, n0 = blockIdx.y * BN;
  const int wm = (w >> 1) * 64, wn = (w & 1) * (BN / 2);
  f32x4 acc[4][NF] = {};
  const int c0 = w * 64 + l, c1 = c0 + 256;
  const int r0 = c0 >> 2, cb0 = (c0 & 3) << 3;
  const int r1 = c1 >> 2, cb1 = (c1 & 3) << 3;
  const int nk = K >> 5;
  for (int kt = 0; kt < nk; ++kt) {
    const int k0 = kt << 5;
    GLDS16(A + (size_t)(m0 + r0) * K + k0 + cb0, smA + (w * 64) * 8);
    GLDS16(A + (size_t)(m0 + r1) * K + k0 + cb1, smA + (256 + w * 64) * 8);
    GLDS16(Bt + (size_t)(n0 + r0) * K + k0 + cb0, smB + (w * 64) * 8);
    if constexpr (BN == 128)
      GLDS16(Bt + (size_t)(n0 + r1) * K + k0 + cb1, smB + (256 + w * 64) * 8);
    __syncthreads();
    bf16x8 af[4], bfr[NF];
#pragma unroll
    for (int m = 0; m < 4; ++m)
      af[m] = *(const bf16x8*)(smA + (wm + m * 16 + lr) * 32 + lg * 8);
#pragma unroll
    for (int n = 0; n < NF; ++n)
      bfr[n] = *(const bf16x8*)(smB + (wn + n * 16 + lr) * 32 + lg * 8);
#pragma unroll
    for (int m = 0; m < 4; ++m)
#pragma unroll
      for (int n = 0; n < NF; ++n)
        acc[m][n] = __builtin_amdgcn_mfma_f32_16x16x32_bf16(af[m], bfr[n], acc[m][n], 0, 0, 0);
    __syncthreads();
  }
#pragma unroll
  for (int m = 0; m < 4; ++m) {
    const int row = m0 + wm + m * 16 + lg * 4;
#pragma unroll
    for (int n = 0; n < NF; ++n) {
      const int col = n0 + wn + n * 16 + lr;
#pragma unroll
      for (int i = 0; i < 4; ++i) {
        float v = acc[m][n][i];
        size_t idx = (size_t)(row + i) * N + col;
        if constexpr (EPI == 0) {
          ((u16*)Cout)[idx] = f2bf(v + bias[col]);
        } else if constexpr (EPI == 2) {
          float cc = v + bias[col];
          float u = 0.7978845608f * (cc + 0.044715f * cc * cc * cc);
          float e = __expf(2.f * u);
          float th = 1.f - 2.f / (e + 1.f);
          ((u16*)Cout)[idx] = f2bf(0.5f * cc * (1.f + th));
        } else {
          ((float*)Cout)[idx] = resid[idx] + gate[col] * (v + bias[col]);
        }
      }
    }
  }
}

// ---------------- q/k: RMS norm + RoPE -> Q,K (h,pos,d) bf16 ----------------
__global__ __launch_bounds__(256)
void qk_post(const u16* __restrict__ qkv_txt, const u16* __restrict__ qkv_img,
             const float* __restrict__ pe,
             const float* __restrict__ iq_s, const float* __restrict__ ik_s,
             const float* __restrict__ tq_s, const float* __restrict__ tk_s,
             u16* __restrict__ Q, u16* __restrict__ K) {
  const int d = threadIdx.x;                       // 0..63
  const int pos = blockIdx.x * 4 + threadIdx.y;    // 0..2303
  const int h = blockIdx.y;
  const u16* src; int r; const float *qs, *ks;
  if (pos < 256) { src = qkv_txt; r = pos; qs = tq_s; ks = tk_s; }
  else           { src = qkv_img; r = pos - 256; qs = iq_s; ks = ik_s; }
  float q = bf2f(src[(size_t)r * 3072 + h * 64 + d]);
  float k = bf2f(src[(size_t)r * 3072 + 1024 + h * 64 + d]);
  float qsq = q * q, ksq = k * k;
#pragma unroll
  for (int o = 32; o; o >>= 1) { qsq += __shfl_xor(qsq, o); ksq += __shfl_xor(ksq, o); }
  q *= rsqrtf(qsq * (1.f / 64.f) + 1e-6f) * qs[d];
  k *= rsqrtf(ksq * (1.f / 64.f) + 1e-6f) * ks[d];
  const int p = d >> 1, odd = d & 1;
  const float* pp = pe + (((size_t)pos * 32 + p) * 2 + odd) * 2;
  float qp = __shfl_xor(q, 1), kp = __shfl_xor(k, 1);
  float qe = odd ? qp : q, qo = odd ? q : qp;
  float ke = odd ? kp : k, ko = odd ? k : kp;
  float rq = pp[0] * qe + pp[1] * qo;
  float rk = pp[0] * ke + pp[1] * ko;
  size_t oidx = ((size_t)h * 2304 + pos) * 64 + d;
  Q[oidx] = f2bf(rq);
  K[oidx] = f2bf(rk);
}

// ---------------- V -> Vt (h, d, pos) bf16 ----------------
__global__ __launch_bounds__(512)
void v_transpose(const u16* __restrict__ qkv_txt, const u16* __restrict__ qkv_img,
                 u16* __restrict__ Vt) {
  __shared__ float tile[64][65];
  const int tx = threadIdx.x, ty = threadIdx.y;   // 64 x 8
  const int p0 = blockIdx.x * 64, h = blockIdx.y;
#pragma unroll
  for (int i = 0; i < 8; ++i) {
    int pos = p0 + ty + i * 8;
    const u16* src; int r;
    if (pos < 256) { src = qkv_txt; r = pos; } else { src = qkv_img; r = pos - 256; }
    tile[ty + i * 8][tx] = bf2f(src[(size_t)r * 3072 + 2048 + h * 64 + tx]);
  }
  __syncthreads();
#pragma unroll
  for (int i = 0; i < 8; ++i) {
    int d = ty + i * 8;
    Vt[((size_t)h * 64 + d) * 2304 + p0 + tx] = f2bf(tile[tx][d]);
  }
}

// ---------------- flash attention ----------------
// Q(h,pos,d) K(h,pos,d) Vt(h,d,pos) -> out (pos, h*64+d) bf16.
// K/V LDS tiles XOR-swizzled (chunk^=row&7) via pre-swizzled global source
// (global_load_lds writes linearly); double-buffered with counted vmcnt.
__global__ __launch_bounds__(256, 3)
void attn_kernel(const u16* __restrict__ Q, const u16* __restrict__ Kb,
                 const u16* __restrict__ Vt, u16* __restrict__ outb) {
  __shared__ u16 smK[2][64 * 64];
  __shared__ u16 smV[2][64 * 64];
  __shared__ u16 smP[4 * 16 * 72];
  const int t = threadIdx.x, w = t >> 6, l = t & 63;
  const int lr = l & 15, lg = l >> 4;
  const int qt = blockIdx.x, h = blockIdx.y;
  const u16* Qp = Q + ((size_t)h * 2304 + qt * 64 + w * 16 + lr) * 64;
  const bf16x8 qf0 = *(const bf16x8*)(Qp + lg * 8);
  const bf16x8 qf1 = *(const bf16x8*)(Qp + 32 + lg * 8);
  const u16* Kbase = Kb + (size_t)h * 2304 * 64;
  const u16* Vbase = Vt + (size_t)h * 64 * 2304;
  f32x4 accO[4] = {};
  float mrow[4] = {-1e30f, -1e30f, -1e30f, -1e30f};
  float lrow[4] = {};
  u16* myP = smP + w * (16 * 72);

  // per-thread staging chunks: c0 = w*64+l (0..255), c1 = c0+256
  const int c0 = w * 64 + l, c1 = c0 + 256;
  const int kr0 = c0 >> 3, ks0 = ((c0 & 7) ^ (kr0 & 7)) * 8;   // swizzled source colgroup
  const int kr1 = c1 >> 3, ks1 = ((c1 & 7) ^ (kr1 & 7)) * 8;

  auto stage = [&](int j, int b) {
    const u16* gK = Kbase + (size_t)j * 64 * 64;
    GLDS16(gK + (size_t)kr0 * 64 + ks0, smK[b] + (w * 64) * 8);
    GLDS16(gK + (size_t)kr1 * 64 + ks1, smK[b] + (256 + w * 64) * 8);
    GLDS16(Vbase + (size_t)kr0 * 2304 + j * 64 + ks0, smV[b] + (w * 64) * 8);
    GLDS16(Vbase + (size_t)kr1 * 2304 + j * 64 + ks1, smV[b] + (256 + w * 64) * 8);
  };

  stage(0, 0);
  for (int j = 0; j < 36; ++j) {
    const int b = j & 1;
    if (j < 35) {
      stage(j + 1, b ^ 1);
      asm volatile("s_waitcnt vmcnt(4)" ::: "memory");   // tile j's 4 loads done
    } else {
      asm volatile("s_waitcnt vmcnt(0)" ::: "memory");
    }
    __builtin_amdgcn_s_barrier();
    asm volatile("" ::: "memory");

    f32x4 sf[4];
#pragma unroll
    for (int n = 0; n < 4; ++n) {
      const int row = n * 16 + lr, sw = row & 7;
      bf16x8 kf0 = *(const bf16x8*)(smK[b] + row * 64 + ((lg ^ sw) << 3));
      bf16x8 kf1 = *(const bf16x8*)(smK[b] + row * 64 + (((lg + 4) ^ sw) << 3));
      f32x4 z = {};
      z = __builtin_amdgcn_mfma_f32_16x16x32_bf16(qf0, kf0, z, 0, 0, 0);
      z = __builtin_amdgcn_mfma_f32_16x16x32_bf16(qf1, kf1, z, 0, 0, 0);
      sf[n] = z * 0.125f;
    }
    float corr[4];
#pragma unroll
    for (int i = 0; i < 4; ++i) {
      float mx = fmaxf(fmaxf(sf[0][i], sf[1][i]), fmaxf(sf[2][i], sf[3][i]));
#pragma unroll
      for (int o = 1; o < 16; o <<= 1) mx = fmaxf(mx, __shfl_xor(mx, o));
      float mnew = fmaxf(mrow[i], mx);
      corr[i] = __expf(mrow[i] - mnew);
      float rs = 0.f;
#pragma unroll
      for (int n = 0; n < 4; ++n) {
        float p = __expf(sf[n][i] - mnew);
        sf[n][i] = p;
        rs += p;
      }
#pragma unroll
      for (int o = 1; o < 16; o <<= 1) rs += __shfl_xor(rs, o);
      lrow[i] = lrow[i] * corr[i] + rs;
      mrow[i] = mnew;
    }
#pragma unroll
    for (int n = 0; n < 4; ++n)
#pragma unroll
      for (int i = 0; i < 4; ++i) {
        accO[n][i] *= corr[i];
        myP[(lg * 4 + i) * 72 + n * 16 + lr] = f2bf(sf[n][i]);
      }
#pragma unroll
    for (int c = 0; c < 2; ++c) {
      bf16x8 pf = *(const bf16x8*)(myP + lr * 72 + c * 32 + lg * 8);
#pragma unroll
      for (int nd = 0; nd < 4; ++nd) {
        const int row = nd * 16 + lr, sw = row & 7;
        bf16x8 vf = *(const bf16x8*)(smV[b] + row * 64 + (((c * 4 + lg) ^ sw) << 3));
        accO[nd] = __builtin_amdgcn_mfma_f32_16x16x32_bf16(pf, vf, accO[nd], 0, 0, 0);
      }
    }
    asm volatile("" ::: "memory");
    __builtin_amdgcn_s_barrier();     // all waves done reading buf b (restaged next iter)
  }
#pragma unroll
  for (int nd = 0; nd < 4; ++nd) {
    const int col = h * 64 + nd * 16 + lr;
#pragma unroll
    for (int i = 0; i < 4; ++i) {
      int row = qt * 64 + w * 16 + lg * 4 + i;
      outb[(size_t)row * 1024 + col] = f2bf(accO[nd][i] / lrow[i]);
    }
  }
}

// ---------------- host ----------------
extern "C" void kernel_launch(void* const* d_in, const int* in_sizes, int n_in,
                              void* d_out, int out_size, void* d_ws, size_t ws_size,
                              hipStream_t stream) {
  const float* img         = (const float*)d_in[0];
  const float* txt         = (const float*)d_in[1];
  const float* pe          = (const float*)d_in[2];
  const float* vec         = (const float*)d_in[3];
  const float* img_mod_w   = (const float*)d_in[4];
  const float* img_mod_b   = (const float*)d_in[5];
  const float* txt_mod_w   = (const float*)d_in[6];
  const float* txt_mod_b   = (const float*)d_in[7];
  const float* img_qkv_w   = (const float*)d_in[8];
  const float* img_qkv_b   = (const float*)d_in[9];
  const float* img_q_scale = (const float*)d_in[10];
  const float* img_k_scale = (const float*)d_in[11];
  const float* img_proj_w  = (const float*)d_in[12];
  const float* img_proj_b  = (const float*)d_in[13];
  const float* txt_qkv_w   = (const float*)d_in[14];
  const float* txt_qkv_b   = (const float*)d_in[15];
  const float* txt_q_scale = (const float*)d_in[16];
  const float* txt_k_scale = (const float*)d_in[17];
  const float* mlp_w1      = (const float*)d_in[18];
  const float* mlp_b1      = (const float*)d_in[19];
  const float* mlp_w2      = (const float*)d_in[20];
  const float* mlp_b2      = (const float*)d_in[21];
  (void)in_sizes; (void)n_in; (void)out_size; (void)ws_size;

  char* ws = (char*)d_ws;
  size_t off = 0;
  auto alloc = [&](size_t bytes) -> void* {
    void* p = ws + off;
    off += (bytes + 255) & ~(size_t)255;
    return p;
  };
  float* sv     = (float*)alloc(1024 * 4);
  float* mod    = (float*)alloc(8192 * 4);
  u16* img_m    = (u16*)alloc((size_t)2048 * 1024 * 2);
  u16* txt_m    = (u16*)alloc((size_t)256 * 1024 * 2);
  u16* wt_iqkv  = (u16*)alloc((size_t)3072 * 1024 * 2);
  u16* wt_tqkv  = (u16*)alloc((size_t)3072 * 1024 * 2);
  u16* wt_proj  = (u16*)alloc((size_t)1024 * 1024 * 2);
  u16* wt_m1    = (u16*)alloc((size_t)4096 * 1024 * 2);
  u16* wt_m2    = (u16*)alloc((size_t)1024 * 4096 * 2);
  u16* qkv_img  = (u16*)alloc((size_t)2048 * 3072 * 2);
  u16* qkv_txt  = (u16*)alloc((size_t)256 * 3072 * 2);
  u16* Qb       = (u16*)alloc((size_t)16 * 2304 * 64 * 2);
  u16* Kb       = (u16*)alloc((size_t)16 * 2304 * 64 * 2);
  u16* Vtb      = (u16*)alloc((size_t)16 * 64 * 2304 * 2);
  u16* attnb    = (u16*)alloc((size_t)2304 * 1024 * 2);
  float* img2   = (float*)alloc((size_t)2048 * 1024 * 4);
  u16* h_in     = (u16*)alloc((size_t)2048 * 1024 * 2);
  u16* h1       = (u16*)alloc((size_t)2048 * 4096 * 2);

  const dim3 bT(32, 8);
  wconv_t<<<dim3(3072 / 32, 1024 / 32), bT, 0, stream>>>(img_qkv_w, wt_iqkv, 1024, 3072);
  wconv_t<<<dim3(3072 / 32, 1024 / 32), bT, 0, stream>>>(txt_qkv_w, wt_tqkv, 1024, 3072);
  wconv_t<<<dim3(1024 / 32, 1024 / 32), bT, 0, stream>>>(img_proj_w, wt_proj, 1024, 1024);
  wconv_t<<<dim3(4096 / 32, 1024 / 32), bT, 0, stream>>>(mlp_w1, wt_m1, 1024, 4096);
  wconv_t<<<dim3(1024 / 32, 4096 / 32), bT, 0, stream>>>(mlp_w2, wt_m2, 4096, 1024);

  silu_kernel<<<4, 256, 0, stream>>>(vec, sv);
  modinit<<<32, 256, 0, stream>>>(img_mod_b, txt_mod_b, mod);
  modgemv<<<dim3(32, 8), 256, 0, stream>>>(sv, img_mod_w, txt_mod_w, mod);

  ln_mod<<<2048, 256, 0, stream>>>(img, mod + 0, mod + 1024, img_m);
  ln_mod<<<256, 256, 0, stream>>>(txt, mod + 6144, mod + 7168, txt_m);

  gemm_bt<0, 128><<<dim3(16, 24), 256, 0, stream>>>(img_m, wt_iqkv, 2048, 3072, 1024,
                                                    img_qkv_b, nullptr, nullptr, qkv_img);
  gemm_bt<0, 128><<<dim3(2, 24), 256, 0, stream>>>(txt_m, wt_tqkv, 256, 3072, 1024,
                                                   txt_qkv_b, nullptr, nullptr, qkv_txt);

  qk_post<<<dim3(576, 16), dim3(64, 4), 0, stream>>>(qkv_txt, qkv_img, pe,
                                                     img_q_scale, img_k_scale,
                                                     txt_q_scale, txt_k_scale, Qb, Kb);
  v_transpose<<<dim3(36, 16), dim3(64, 8), 0, stream>>>(qkv_txt, qkv_img, Vtb);

  attn_kernel<<<dim3(36, 16), 256, 0, stream>>>(Qb, Kb, Vtb, attnb);

  gemm_bt<1, 64><<<dim3(16, 16), 256, 0, stream>>>(attnb + (size_t)256 * 1024, wt_proj,
                                                   2048, 1024, 1024,
                                                   img_proj_b, mod + 2048, img, img2);
  ln_mod<<<2048, 256, 0, stream>>>(img2, mod + 3072, mod + 4096, h_in);
  gemm_bt<2, 128><<<dim3(16, 32), 256, 0, stream>>>(h_in, wt_m1, 2048, 4096, 1024,
                                                    mlp_b1, nullptr, nullptr, h1);
  gemm_bt<3, 64><<<dim3(16, 16), 256, 0, stream>>>(h1, wt_m2, 2048, 1024, 4096,
                                                   mlp_b2, mod + 5120, img2, (float*)d_out);
}

// Round 4
// 442.540 us; speedup vs baseline: 1.1638x; 1.0670x over previous
//
#include <hip/hip_runtime.h>
#include <cstdint>
#include <cstddef>

typedef unsigned short u16;
typedef __attribute__((ext_vector_type(8))) short bf16x8;
typedef __attribute__((ext_vector_type(4))) float f32x4;

#define AS1 __attribute__((address_space(1)))
#define AS3 __attribute__((address_space(3)))
#define GLDS16(g, s) __builtin_amdgcn_global_load_lds((const AS1 void*)(g), (AS3 void*)(s), 16, 0, 0)

__device__ inline u16 f2bf(float f) {
  union { float f; unsigned u; } c; c.f = f;
  unsigned r = c.u + 0x7fffu + ((c.u >> 16) & 1u);
  return (u16)(r >> 16);
}
__device__ inline float bf2f(u16 s) {
  union { unsigned u; float f; } c; c.u = ((unsigned)s) << 16;
  return c.f;
}
__device__ inline unsigned cvt_pk_bf16(float a, float b) {
  unsigned r;
  asm("v_cvt_pk_bf16_f32 %0, %1, %2" : "=v"(r) : "v"(a), "v"(b));
  return r;
}

// ---------------- weight f32 (K,N) -> bf16 (N,K) ----------------
__global__ __launch_bounds__(256)
void wconv_t(const float* __restrict__ W, u16* __restrict__ Wt, int K, int N) {
  __shared__ float tile[32][33];
  const int tx = threadIdx.x, ty = threadIdx.y;
  const int n0 = blockIdx.x * 32, k0 = blockIdx.y * 32;
#pragma unroll
  for (int i = 0; i < 4; ++i)
    tile[ty + i * 8][tx] = W[(size_t)(k0 + ty + i * 8) * N + n0 + tx];
  __syncthreads();
#pragma unroll
  for (int i = 0; i < 4; ++i)
    Wt[(size_t)(n0 + ty + i * 8) * K + k0 + tx] = f2bf(tile[tx][ty + i * 8]);
}

// ---------------- modulation ----------------
__global__ __launch_bounds__(256)
void silu_kernel(const float* __restrict__ vec, float* __restrict__ sv) {
  int i = blockIdx.x * 256 + threadIdx.x;
  float x = vec[i];
  sv[i] = x / (1.f + __expf(-x));
}

__global__ __launch_bounds__(256)
void modinit(const float* __restrict__ imb, const float* __restrict__ tmb, float* __restrict__ mod) {
  int i = blockIdx.x * 256 + threadIdx.x;  // 8192
  mod[i] = (i < 6144) ? imb[i] : tmb[i - 6144];
}

__global__ __launch_bounds__(256)
void modgemv(const float* __restrict__ sv, const float* __restrict__ imw,
             const float* __restrict__ tmw, float* __restrict__ mod) {
  __shared__ float s[128];
  const int t = threadIdx.x;
  const int c = blockIdx.x * 256 + t;       // 0..8191
  const int kc = blockIdx.y * 128;          // k chunk
  if (t < 128) s[t] = sv[kc + t];
  __syncthreads();
  const float* W; int col;
  if (c < 6144) { W = imw; col = c; } else { W = tmw; col = c - 6144; }
  float acc = 0.f;
#pragma unroll 8
  for (int k = 0; k < 128; ++k) acc += s[k] * W[(size_t)(kc + k) * 6144 + col];
  atomicAdd(&mod[c], acc);
}

// ---------------- LayerNorm + modulate -> bf16 ----------------
__global__ __launch_bounds__(256)
void ln_mod(const float* __restrict__ x, const float* __restrict__ shift,
            const float* __restrict__ scale, u16* __restrict__ out) {
  const int row = blockIdx.x, t = threadIdx.x;
  const float* xr = x + (size_t)row * 1024;
  float v[4], s = 0.f, sq = 0.f;
#pragma unroll
  for (int i = 0; i < 4; ++i) { v[i] = xr[t + i * 256]; s += v[i]; sq += v[i] * v[i]; }
#pragma unroll
  for (int o = 32; o; o >>= 1) { s += __shfl_down(s, o); sq += __shfl_down(sq, o); }
  __shared__ float ls[8];
  if ((t & 63) == 0) { ls[t >> 6] = s; ls[4 + (t >> 6)] = sq; }
  __syncthreads();
  s = ls[0] + ls[1] + ls[2] + ls[3];
  sq = ls[4] + ls[5] + ls[6] + ls[7];
  const float mean = s * (1.f / 1024.f);
  const float var = sq * (1.f / 1024.f) - mean * mean;
  const float rstd = rsqrtf(var + 1e-6f);
#pragma unroll
  for (int i = 0; i < 4; ++i) {
    int c = t + i * 256;
    float xn = (v[i] - mean) * rstd;
    out[(size_t)row * 1024 + c] = f2bf((1.f + scale[c]) * xn + shift[c]);
  }
}

// ---------------- GEMM: C = A(MxK) * Bt(NxK)^T, bf16 in, fused epilogues ----------------
template <int EPI, int BN>
__global__ __launch_bounds__(256, 3)
void gemm_bt(const u16* __restrict__ A, const u16* __restrict__ Bt,
             int M, int N, int K,
             const float* __restrict__ bias, const float* __restrict__ gate,
             const float* __restrict__ resid, void* __restrict__ Cout) {
  constexpr int NF = BN / 32;               // n-fragments per wave
  __shared__ u16 smA[128 * 32];
  __shared__ u16 smB[BN * 32];
  const int t = threadIdx.x;
  const int w = t >> 6, l = t & 63;
  const int lr = l & 15, lg = l >> 4;
  const int m0 = blockIdx.x * 128, n0 = blockIdx.y * BN;
  const int wm = (w >> 1) * 64, wn = (w & 1) * (BN / 2);
  f32x4 acc[4][NF] = {};
  const int c0 = w * 64 + l, c1 = c0 + 256;
  const int r0 = c0 >> 2, cb0 = (c0 & 3) << 3;
  const int r1 = c1 >> 2, cb1 = (c1 & 3) << 3;
  const int nk = K >> 5;
  for (int kt = 0; kt < nk; ++kt) {
    const int k0 = kt << 5;
    GLDS16(A + (size_t)(m0 + r0) * K + k0 + cb0, smA + (w * 64) * 8);
    GLDS16(A + (size_t)(m0 + r1) * K + k0 + cb1, smA + (256 + w * 64) * 8);
    GLDS16(Bt + (size_t)(n0 + r0) * K + k0 + cb0, smB + (w * 64) * 8);
    if constexpr (BN == 128)
      GLDS16(Bt + (size_t)(n0 + r1) * K + k0 + cb1, smB + (256 + w * 64) * 8);
    __syncthreads();
    bf16x8 af[4], bfr[NF];
#pragma unroll
    for (int m = 0; m < 4; ++m)
      af[m] = *(const bf16x8*)(smA + (wm + m * 16 + lr) * 32 + lg * 8);
#pragma unroll
    for (int n = 0; n < NF; ++n)
      bfr[n] = *(const bf16x8*)(smB + (wn + n * 16 + lr) * 32 + lg * 8);
#pragma unroll
    for (int m = 0; m < 4; ++m)
#pragma unroll
      for (int n = 0; n < NF; ++n)
        acc[m][n] = __builtin_amdgcn_mfma_f32_16x16x32_bf16(af[m], bfr[n], acc[m][n], 0, 0, 0);
    __syncthreads();
  }
#pragma unroll
  for (int m = 0; m < 4; ++m) {
    const int row = m0 + wm + m * 16 + lg * 4;
#pragma unroll
    for (int n = 0; n < NF; ++n) {
      const int col = n0 + wn + n * 16 + lr;
#pragma unroll
      for (int i = 0; i < 4; ++i) {
        float v = acc[m][n][i];
        size_t idx = (size_t)(row + i) * N + col;
        if constexpr (EPI == 0) {
          ((u16*)Cout)[idx] = f2bf(v + bias[col]);
        } else if constexpr (EPI == 2) {
          float cc = v + bias[col];
          float u = 0.7978845608f * (cc + 0.044715f * cc * cc * cc);
          float e = __expf(2.f * u);
          float th = 1.f - 2.f / (e + 1.f);
          ((u16*)Cout)[idx] = f2bf(0.5f * cc * (1.f + th));
        } else {
          ((float*)Cout)[idx] = resid[idx] + gate[col] * (v + bias[col]);
        }
      }
    }
  }
}

// ---------------- q/k: RMS norm + RoPE -> Q,K (h,pos,d) bf16 ----------------
// Q is pre-scaled by 1/8 (softmax scale folded here).
__global__ __launch_bounds__(256)
void qk_post(const u16* __restrict__ qkv_txt, const u16* __restrict__ qkv_img,
             const float* __restrict__ pe,
             const float* __restrict__ iq_s, const float* __restrict__ ik_s,
             const float* __restrict__ tq_s, const float* __restrict__ tk_s,
             u16* __restrict__ Q, u16* __restrict__ K) {
  const int d = threadIdx.x;                       // 0..63
  const int pos = blockIdx.x * 4 + threadIdx.y;    // 0..2303
  const int h = blockIdx.y;
  const u16* src; int r; const float *qs, *ks;
  if (pos < 256) { src = qkv_txt; r = pos; qs = tq_s; ks = tk_s; }
  else           { src = qkv_img; r = pos - 256; qs = iq_s; ks = ik_s; }
  float q = bf2f(src[(size_t)r * 3072 + h * 64 + d]);
  float k = bf2f(src[(size_t)r * 3072 + 1024 + h * 64 + d]);
  float qsq = q * q, ksq = k * k;
#pragma unroll
  for (int o = 32; o; o >>= 1) { qsq += __shfl_xor(qsq, o); ksq += __shfl_xor(ksq, o); }
  q *= rsqrtf(qsq * (1.f / 64.f) + 1e-6f) * qs[d];
  k *= rsqrtf(ksq * (1.f / 64.f) + 1e-6f) * ks[d];
  const int p = d >> 1, odd = d & 1;
  const float* pp = pe + (((size_t)pos * 32 + p) * 2 + odd) * 2;
  float qp = __shfl_xor(q, 1), kp = __shfl_xor(k, 1);
  float qe = odd ? qp : q, qo = odd ? q : qp;
  float ke = odd ? kp : k, ko = odd ? k : kp;
  float rq = pp[0] * qe + pp[1] * qo;
  float rk = pp[0] * ke + pp[1] * ko;
  size_t oidx = ((size_t)h * 2304 + pos) * 64 + d;
  Q[oidx] = f2bf(rq * 0.125f);
  K[oidx] = f2bf(rk);
}

// ---------------- V -> Vt (h, d, pos) bf16 ----------------
__global__ __launch_bounds__(512)
void v_transpose(const u16* __restrict__ qkv_txt, const u16* __restrict__ qkv_img,
                 u16* __restrict__ Vt) {
  __shared__ float tile[64][65];
  const int tx = threadIdx.x, ty = threadIdx.y;   // 64 x 8
  const int p0 = blockIdx.x * 64, h = blockIdx.y;
#pragma unroll
  for (int i = 0; i < 8; ++i) {
    int pos = p0 + ty + i * 8;
    const u16* src; int r;
    if (pos < 256) { src = qkv_txt; r = pos; } else { src = qkv_img; r = pos - 256; }
    tile[ty + i * 8][tx] = bf2f(src[(size_t)r * 3072 + 2048 + h * 64 + tx]);
  }
  __syncthreads();
#pragma unroll
  for (int i = 0; i < 8; ++i) {
    int d = ty + i * 8;
    Vt[((size_t)h * 64 + d) * 2304 + p0 + tx] = f2bf(tile[tx][d]);
  }
}

// ---------------- flash attention (split-KV, swapped QK^T) ----------------
// Q(h,pos,d)*1/8, K(h,pos,d), Vt(h,d,pos) -> Opart f32 + ml (m,l) per split.
// Swapped MFMA: S^T = mfma(K, Q) puts all 16 k-scores of one q in-lane:
// lane(lr,lg): q = lr, k = n*16 + lg*4 + i. k-reduce = in-reg tree + 2 shfl.
__global__ __launch_bounds__(256, 3)
void attn_kernel(const u16* __restrict__ Q, const u16* __restrict__ Kb,
                 const u16* __restrict__ Vt,
                 float* __restrict__ Opart, float* __restrict__ ml) {
  __shared__ u16 smK[2][64 * 64];
  __shared__ u16 smV[2][64 * 64];
  __shared__ u16 smP[4 * 16 * 72];
  const int t = threadIdx.x, w = t >> 6, l = t & 63;
  const int lr = l & 15, lg = l >> 4;
  const int qt = blockIdx.x, h = blockIdx.y, sp = blockIdx.z;
  const int j0 = sp * 18;
  const u16* Qp = Q + ((size_t)h * 2304 + qt * 64 + w * 16 + lr) * 64;
  const bf16x8 qf0 = *(const bf16x8*)(Qp + lg * 8);
  const bf16x8 qf1 = *(const bf16x8*)(Qp + 32 + lg * 8);
  const u16* Kbase = Kb + (size_t)h * 2304 * 64;
  const u16* Vbase = Vt + (size_t)h * 64 * 2304;
  f32x4 accO[4] = {};
  float mrun = -1e30f, lrun = 0.f;
  u16* myP = smP + w * (16 * 72);

  const int c0 = w * 64 + l, c1 = c0 + 256;
  const int kr0 = c0 >> 3, ks0 = ((c0 & 7) ^ (kr0 & 7)) * 8;   // swizzled source colgroup
  const int kr1 = c1 >> 3, ks1 = ((c1 & 7) ^ (kr1 & 7)) * 8;

  auto stage = [&](int j, int b) {
    const u16* gK = Kbase + (size_t)j * 64 * 64;
    GLDS16(gK + (size_t)kr0 * 64 + ks0, smK[b] + (w * 64) * 8);
    GLDS16(gK + (size_t)kr1 * 64 + ks1, smK[b] + (256 + w * 64) * 8);
    GLDS16(Vbase + (size_t)kr0 * 2304 + j * 64 + ks0, smV[b] + (w * 64) * 8);
    GLDS16(Vbase + (size_t)kr1 * 2304 + j * 64 + ks1, smV[b] + (256 + w * 64) * 8);
  };

  stage(j0, 0);
  for (int jj = 0; jj < 18; ++jj) {
    const int b = jj & 1;
    if (jj < 17) {
      stage(j0 + jj + 1, b ^ 1);
      asm volatile("s_waitcnt vmcnt(4)" ::: "memory");
    } else {
      asm volatile("s_waitcnt vmcnt(0)" ::: "memory");
    }
    __builtin_amdgcn_s_barrier();
    asm volatile("" ::: "memory");

    // S^T = K * Q^T : sf[n][i] = S[k = n*16+lg*4+i][q = lr]
    f32x4 sf[4];
    __builtin_amdgcn_s_setprio(1);
#pragma unroll
    for (int n = 0; n < 4; ++n) {
      const int row = n * 16 + lr, sw = row & 7;
      bf16x8 kf0 = *(const bf16x8*)(smK[b] + row * 64 + ((lg ^ sw) << 3));
      bf16x8 kf1 = *(const bf16x8*)(smK[b] + row * 64 + (((lg + 4) ^ sw) << 3));
      f32x4 z = {};
      z = __builtin_amdgcn_mfma_f32_16x16x32_bf16(kf0, qf0, z, 0, 0, 0);
      z = __builtin_amdgcn_mfma_f32_16x16x32_bf16(kf1, qf1, z, 0, 0, 0);
      sf[n] = z;
    }
    __builtin_amdgcn_s_setprio(0);

    // in-register max tree over 16 + 2-step shfl over lg groups
    float t0 = fmaxf(fmaxf(sf[0][0], sf[0][1]), fmaxf(sf[0][2], sf[0][3]));
    float t1 = fmaxf(fmaxf(sf[1][0], sf[1][1]), fmaxf(sf[1][2], sf[1][3]));
    float t2 = fmaxf(fmaxf(sf[2][0], sf[2][1]), fmaxf(sf[2][2], sf[2][3]));
    float t3 = fmaxf(fmaxf(sf[3][0], sf[3][1]), fmaxf(sf[3][2], sf[3][3]));
    float mx = fmaxf(fmaxf(t0, t1), fmaxf(t2, t3));
    mx = fmaxf(mx, __shfl_xor(mx, 16));
    mx = fmaxf(mx, __shfl_xor(mx, 32));
    const float mnew = fmaxf(mrun, mx);
    const float corr = __expf(mrun - mnew);
    mrun = mnew;

    float p[4][4];
    float s0 = 0.f, s1 = 0.f, s2 = 0.f, s3 = 0.f;
#pragma unroll
    for (int n = 0; n < 4; ++n) {
      p[n][0] = __expf(sf[n][0] - mnew);
      p[n][1] = __expf(sf[n][1] - mnew);
      p[n][2] = __expf(sf[n][2] - mnew);
      p[n][3] = __expf(sf[n][3] - mnew);
    }
    s0 = (p[0][0] + p[0][1]) + (p[0][2] + p[0][3]);
    s1 = (p[1][0] + p[1][1]) + (p[1][2] + p[1][3]);
    s2 = (p[2][0] + p[2][1]) + (p[2][2] + p[2][3]);
    s3 = (p[3][0] + p[3][1]) + (p[3][2] + p[3][3]);
    float rs = (s0 + s1) + (s2 + s3);
    rs += __shfl_xor(rs, 16);
    rs += __shfl_xor(rs, 32);
    lrun = lrun * corr + rs;

    // P store: pairs are k-adjacent -> cvt_pk + b32 writes. myP[q][k], stride 72.
#pragma unroll
    for (int n = 0; n < 4; ++n) {
      *(unsigned*)(myP + lr * 72 + n * 16 + lg * 4)     = cvt_pk_bf16(p[n][0], p[n][1]);
      *(unsigned*)(myP + lr * 72 + n * 16 + lg * 4 + 2) = cvt_pk_bf16(p[n][2], p[n][3]);
    }

    // rescale accO: C-row q-index = lg*4+i, corr lives in lane (q, lg=0..3)
    float cb[4];
#pragma unroll
    for (int i = 0; i < 4; ++i) cb[i] = __shfl(corr, lg * 4 + i);
#pragma unroll
    for (int nd = 0; nd < 4; ++nd)
#pragma unroll
      for (int i = 0; i < 4; ++i) accO[nd][i] *= cb[i];

    // PV: O += P * V  (A = P rows=q, B = V rows=d)
    __builtin_amdgcn_s_setprio(1);
#pragma unroll
    for (int c = 0; c < 2; ++c) {
      bf16x8 pf = *(const bf16x8*)(myP + lr * 72 + c * 32 + lg * 8);
#pragma unroll
      for (int nd = 0; nd < 4; ++nd) {
        const int row = nd * 16 + lr, sw = row & 7;
        bf16x8 vf = *(const bf16x8*)(smV[b] + row * 64 + (((c * 4 + lg) ^ sw) << 3));
        accO[nd] = __builtin_amdgcn_mfma_f32_16x16x32_bf16(pf, vf, accO[nd], 0, 0, 0);
      }
    }
    __builtin_amdgcn_s_setprio(0);
    asm volatile("" ::: "memory");
    __builtin_amdgcn_s_barrier();
  }

  // write partials (unnormalized) + m,l
  float* Op = Opart + (((size_t)(sp * 16 + h) * 2304) + qt * 64) * 64;
#pragma unroll
  for (int nd = 0; nd < 4; ++nd)
#pragma unroll
    for (int i = 0; i < 4; ++i)
      Op[(size_t)(w * 16 + lg * 4 + i) * 64 + nd * 16 + lr] = accO[nd][i];
  if (lg == 0) {
    size_t mi = ((size_t)(sp * 16 + h) * 2304 + qt * 64 + w * 16 + lr) * 2;
    ml[mi] = mrun;
    ml[mi + 1] = lrun;
  }
}

// ---------------- combine split-KV partials -> out (pos, h*64+d) bf16 ----------------
__global__ __launch_bounds__(256)
void attn_combine(const float* __restrict__ Opart, const float* __restrict__ ml,
                  u16* __restrict__ outb) {
  int idx = blockIdx.x * 256 + threadIdx.x;       // over 2304*1024
  int q = idx >> 10, c = idx & 1023;
  int h = c >> 6, d = c & 63;
  size_t i0 = (size_t)h * 2304 + q;
  size_t i1 = (size_t)(16 + h) * 2304 + q;
  float m0 = ml[i0 * 2], l0 = ml[i0 * 2 + 1];
  float m1 = ml[i1 * 2], l1 = ml[i1 * 2 + 1];
  float M = fmaxf(m0, m1);
  float w0 = __expf(m0 - M), w1 = __expf(m1 - M);
  float a0 = Opart[i0 * 64 + d], a1 = Opart[i1 * 64 + d];
  float num = w0 * a0 + w1 * a1;
  float den = w0 * l0 + w1 * l1;
  outb[(size_t)q * 1024 + c] = f2bf(num / den);
}

// ---------------- host ----------------
extern "C" void kernel_launch(void* const* d_in, const int* in_sizes, int n_in,
                              void* d_out, int out_size, void* d_ws, size_t ws_size,
                              hipStream_t stream) {
  const float* img         = (const float*)d_in[0];
  const float* txt         = (const float*)d_in[1];
  const float* pe          = (const float*)d_in[2];
  const float* vec         = (const float*)d_in[3];
  const float* img_mod_w   = (const float*)d_in[4];
  const float* img_mod_b   = (const float*)d_in[5];
  const float* txt_mod_w   = (const float*)d_in[6];
  const float* txt_mod_b   = (const float*)d_in[7];
  const float* img_qkv_w   = (const float*)d_in[8];
  const float* img_qkv_b   = (const float*)d_in[9];
  const float* img_q_scale = (const float*)d_in[10];
  const float* img_k_scale = (const float*)d_in[11];
  const float* img_proj_w  = (const float*)d_in[12];
  const float* img_proj_b  = (const float*)d_in[13];
  const float* txt_qkv_w   = (const float*)d_in[14];
  const float* txt_qkv_b   = (const float*)d_in[15];
  const float* txt_q_scale = (const float*)d_in[16];
  const float* txt_k_scale = (const float*)d_in[17];
  const float* mlp_w1      = (const float*)d_in[18];
  const float* mlp_b1      = (const float*)d_in[19];
  const float* mlp_w2      = (const float*)d_in[20];
  const float* mlp_b2      = (const float*)d_in[21];
  (void)in_sizes; (void)n_in; (void)out_size; (void)ws_size;

  char* ws = (char*)d_ws;
  size_t off = 0;
  auto alloc = [&](size_t bytes) -> void* {
    void* p = ws + off;
    off += (bytes + 255) & ~(size_t)255;
    return p;
  };
  float* sv     = (float*)alloc(1024 * 4);
  float* mod    = (float*)alloc(8192 * 4);
  // --- aliased region: {qkv_img, qkv_txt, img_m, txt_m} (18,874,368 B) == Opart ---
  u16* qkv_img  = (u16*)alloc((size_t)2048 * 3072 * 2);   // 12,582,912
  u16* qkv_txt  = (u16*)alloc((size_t)256 * 3072 * 2);    //  1,572,864
  u16* img_m    = (u16*)alloc((size_t)2048 * 1024 * 2);   //  4,194,304
  u16* txt_m    = (u16*)alloc((size_t)256 * 1024 * 2);    //    524,288
  float* Opart  = (float*)qkv_img;                        // 2*16*2304*64*4 = 18,874,368
  float* mlbuf  = (float*)alloc((size_t)2 * 16 * 2304 * 2 * 4);
  u16* wt_iqkv  = (u16*)alloc((size_t)3072 * 1024 * 2);
  u16* wt_tqkv  = (u16*)alloc((size_t)3072 * 1024 * 2);
  u16* wt_proj  = (u16*)alloc((size_t)1024 * 1024 * 2);
  u16* wt_m1    = (u16*)alloc((size_t)4096 * 1024 * 2);
  u16* wt_m2    = (u16*)alloc((size_t)1024 * 4096 * 2);
  u16* Qb       = (u16*)alloc((size_t)16 * 2304 * 64 * 2);
  u16* Kb       = (u16*)alloc((size_t)16 * 2304 * 64 * 2);
  u16* Vtb      = (u16*)alloc((size_t)16 * 64 * 2304 * 2);
  u16* attnb    = (u16*)alloc((size_t)2304 * 1024 * 2);
  float* img2   = (float*)alloc((size_t)2048 * 1024 * 4);
  u16* h_in     = (u16*)alloc((size_t)2048 * 1024 * 2);
  u16* h1       = (u16*)alloc((size_t)2048 * 4096 * 2);

  const dim3 bT(32, 8);
  wconv_t<<<dim3(3072 / 32, 1024 / 32), bT, 0, stream>>>(img_qkv_w, wt_iqkv, 1024, 3072);
  wconv_t<<<dim3(3072 / 32, 1024 / 32), bT, 0, stream>>>(txt_qkv_w, wt_tqkv, 1024, 3072);
  wconv_t<<<dim3(1024 / 32, 1024 / 32), bT, 0, stream>>>(img_proj_w, wt_proj, 1024, 1024);
  wconv_t<<<dim3(4096 / 32, 1024 / 32), bT, 0, stream>>>(mlp_w1, wt_m1, 1024, 4096);
  wconv_t<<<dim3(1024 / 32, 4096 / 32), bT, 0, stream>>>(mlp_w2, wt_m2, 4096, 1024);

  silu_kernel<<<4, 256, 0, stream>>>(vec, sv);
  modinit<<<32, 256, 0, stream>>>(img_mod_b, txt_mod_b, mod);
  modgemv<<<dim3(32, 8), 256, 0, stream>>>(sv, img_mod_w, txt_mod_w, mod);

  ln_mod<<<2048, 256, 0, stream>>>(img, mod + 0, mod + 1024, img_m);
  ln_mod<<<256, 256, 0, stream>>>(txt, mod + 6144, mod + 7168, txt_m);

  gemm_bt<0, 128><<<dim3(16, 24), 256, 0, stream>>>(img_m, wt_iqkv, 2048, 3072, 1024,
                                                    img_qkv_b, nullptr, nullptr, qkv_img);
  gemm_bt<0, 128><<<dim3(2, 24), 256, 0, stream>>>(txt_m, wt_tqkv, 256, 3072, 1024,
                                                   txt_qkv_b, nullptr, nullptr, qkv_txt);

  qk_post<<<dim3(576, 16), dim3(64, 4), 0, stream>>>(qkv_txt, qkv_img, pe,
                                                     img_q_scale, img_k_scale,
                                                     txt_q_scale, txt_k_scale, Qb, Kb);
  v_transpose<<<dim3(36, 16), dim3(64, 8), 0, stream>>>(qkv_txt, qkv_img, Vtb);

  // qkv_img/qkv_txt/img_m/txt_m are dead past here; Opart aliases them.
  attn_kernel<<<dim3(36, 16, 2), 256, 0, stream>>>(Qb, Kb, Vtb, Opart, mlbuf);
  attn_combine<<<9216, 256, 0, stream>>>(Opart, mlbuf, attnb);

  gemm_bt<1, 64><<<dim3(16, 16), 256, 0, stream>>>(attnb + (size_t)256 * 1024, wt_proj,
                                                   2048, 1024, 1024,
                                                   img_proj_b, mod + 2048, img, img2);
  ln_mod<<<2048, 256, 0, stream>>>(img2, mod + 3072, mod + 4096, h_in);
  gemm_bt<2, 128><<<dim3(16, 32), 256, 0, stream>>>(h_in, wt_m1, 2048, 4096, 1024,
                                                    mlp_b1, nullptr, nullptr, h1);
  gemm_bt<3, 64><<<dim3(16, 16), 256, 0, stream>>>(h1, wt_m2, 2048, 1024, 4096,
                                                   mlp_b2, mod + 5120, img2, (float*)d_out);
}

// Round 5
// 411.915 us; speedup vs baseline: 1.2504x; 1.0743x over previous
//
#include <hip/hip_runtime.h>
#include <cstdint>
#include <cstddef>

typedef unsigned short u16;
typedef __attribute__((ext_vector_type(8))) short bf16x8;
typedef __attribute__((ext_vector_type(4))) float f32x4;

#define AS1 __attribute__((address_space(1)))
#define AS3 __attribute__((address_space(3)))
#define GLDS16(g, s) __builtin_amdgcn_global_load_lds((const AS1 void*)(g), (AS3 void*)(s), 16, 0, 0)

__device__ inline u16 f2bf(float f) {
  union { float f; unsigned u; } c; c.f = f;
  unsigned r = c.u + 0x7fffu + ((c.u >> 16) & 1u);
  return (u16)(r >> 16);
}
__device__ inline float bf2f(u16 s) {
  union { unsigned u; float f; } c; c.u = ((unsigned)s) << 16;
  return c.f;
}
__device__ inline unsigned cvt_pk_bf16(float a, float b) {
  unsigned r;
  asm("v_cvt_pk_bf16_f32 %0, %1, %2" : "=v"(r) : "v"(a), "v"(b));
  return r;
}

// ---------------- weight f32 (K,N) -> bf16 (N,K) ----------------
__global__ __launch_bounds__(256)
void wconv_t(const float* __restrict__ W, u16* __restrict__ Wt, int K, int N) {
  __shared__ float tile[32][33];
  const int tx = threadIdx.x, ty = threadIdx.y;
  const int n0 = blockIdx.x * 32, k0 = blockIdx.y * 32;
#pragma unroll
  for (int i = 0; i < 4; ++i)
    tile[ty + i * 8][tx] = W[(size_t)(k0 + ty + i * 8) * N + n0 + tx];
  __syncthreads();
#pragma unroll
  for (int i = 0; i < 4; ++i)
    Wt[(size_t)(n0 + ty + i * 8) * K + k0 + tx] = f2bf(tile[tx][ty + i * 8]);
}

// ---------------- modulation ----------------
__global__ __launch_bounds__(256)
void silu_kernel(const float* __restrict__ vec, float* __restrict__ sv) {
  int i = blockIdx.x * 256 + threadIdx.x;
  float x = vec[i];
  sv[i] = x / (1.f + __expf(-x));
}

__global__ __launch_bounds__(256)
void modinit(const float* __restrict__ imb, const float* __restrict__ tmb, float* __restrict__ mod) {
  int i = blockIdx.x * 256 + threadIdx.x;  // 8192
  mod[i] = (i < 6144) ? imb[i] : tmb[i - 6144];
}

__global__ __launch_bounds__(256)
void modgemv(const float* __restrict__ sv, const float* __restrict__ imw,
             const float* __restrict__ tmw, float* __restrict__ mod) {
  __shared__ float s[128];
  const int t = threadIdx.x;
  const int c = blockIdx.x * 256 + t;       // 0..8191
  const int kc = blockIdx.y * 128;          // k chunk
  if (t < 128) s[t] = sv[kc + t];
  __syncthreads();
  const float* W; int col;
  if (c < 6144) { W = imw; col = c; } else { W = tmw; col = c - 6144; }
  float acc = 0.f;
#pragma unroll 8
  for (int k = 0; k < 128; ++k) acc += s[k] * W[(size_t)(kc + k) * 6144 + col];
  atomicAdd(&mod[c], acc);
}

// ---------------- LayerNorm + modulate -> bf16 ----------------
__global__ __launch_bounds__(256)
void ln_mod(const float* __restrict__ x, const float* __restrict__ shift,
            const float* __restrict__ scale, u16* __restrict__ out) {
  const int row = blockIdx.x, t = threadIdx.x;
  const float* xr = x + (size_t)row * 1024;
  float v[4], s = 0.f, sq = 0.f;
#pragma unroll
  for (int i = 0; i < 4; ++i) { v[i] = xr[t + i * 256]; s += v[i]; sq += v[i] * v[i]; }
#pragma unroll
  for (int o = 32; o; o >>= 1) { s += __shfl_down(s, o); sq += __shfl_down(sq, o); }
  __shared__ float ls[8];
  if ((t & 63) == 0) { ls[t >> 6] = s; ls[4 + (t >> 6)] = sq; }
  __syncthreads();
  s = ls[0] + ls[1] + ls[2] + ls[3];
  sq = ls[4] + ls[5] + ls[6] + ls[7];
  const float mean = s * (1.f / 1024.f);
  const float var = sq * (1.f / 1024.f) - mean * mean;
  const float rstd = rsqrtf(var + 1e-6f);
#pragma unroll
  for (int i = 0; i < 4; ++i) {
    int c = t + i * 256;
    float xn = (v[i] - mean) * rstd;
    out[(size_t)row * 1024 + c] = f2bf((1.f + scale[c]) * xn + shift[c]);
  }
}

// ---------------- GEMM: C = A(MxK)*Bt(NxK)^T, bf16, dbuf + swizzled LDS ----------------
// EPI 0: bf16 = acc+bias ; 1/3: f32 = resid+gate*(acc+bias) ; 2: bf16 = gelu(acc+bias)
// EPI 4: f32 partial (split-K, offset blockIdx.z*M*N, no bias)
// LDS swizzle: 16B-chunk' = chunk ^ ((row>>1)&3), applied to global source (linear
// global_load_lds dest) and to fragment reads -> 2 lanes/bank (free).
template <int EPI, int BM, int BN>
__global__ __launch_bounds__(256, 3)
void gemm_bt(const u16* __restrict__ A, const u16* __restrict__ Bt,
             int M, int N, int Kstride, int Kspan,
             const float* __restrict__ bias, const float* __restrict__ gate,
             const float* __restrict__ resid, void* __restrict__ Cout) {
  constexpr int MF = BM / 32, NF = BN / 32, L = (BM + BN) / 64;
  __shared__ u16 smA[2][BM * 32];
  __shared__ u16 smB[2][BN * 32];
  const int t = threadIdx.x;
  const int w = t >> 6, l = t & 63;
  const int lr = l & 15, lg = l >> 4;
  const int m0 = blockIdx.x * BM, n0 = blockIdx.y * BN;
  const int koff = blockIdx.z * Kspan;
  const int wm = (w >> 1) * (BM / 2), wn = (w & 1) * (BN / 2);
  f32x4 acc[MF][NF] = {};

  // per-thread staging assignment (16B chunks, pre-swizzled global source)
  const u16* gb[L];
  int doff[L];
  bool isA[L];
#pragma unroll
  for (int i = 0; i < L; ++i) {
    int c = t + i * 256;
    if (c < BM * 4) {
      int row = c >> 2, ch = c & 3;
      gb[i] = A + (size_t)(m0 + row) * Kstride + koff + ((ch ^ ((row >> 1) & 3)) << 3);
      doff[i] = c * 8; isA[i] = true;
    } else {
      int cc = c - BM * 4, row = cc >> 2, ch = cc & 3;
      gb[i] = Bt + (size_t)(n0 + row) * Kstride + koff + ((ch ^ ((row >> 1) & 3)) << 3);
      doff[i] = cc * 8; isA[i] = false;
    }
  }
  auto stage = [&](int kt, int b) {
#pragma unroll
    for (int i = 0; i < L; ++i)
      GLDS16(gb[i] + (kt << 5), (isA[i] ? smA[b] : smB[b]) + doff[i]);
  };

  const int nk = Kspan >> 5;
  stage(0, 0);
  for (int kt = 0; kt < nk; ++kt) {
    const int b = kt & 1;
    if (kt < nk - 1) {
      stage(kt + 1, b ^ 1);
      if constexpr (L == 4)      asm volatile("s_waitcnt vmcnt(4)" ::: "memory");
      else if constexpr (L == 3) asm volatile("s_waitcnt vmcnt(3)" ::: "memory");
      else                       asm volatile("s_waitcnt vmcnt(2)" ::: "memory");
    } else {
      asm volatile("s_waitcnt vmcnt(0)" ::: "memory");
    }
    __builtin_amdgcn_s_barrier();
    asm volatile("" ::: "memory");

    bf16x8 af[MF], bfr[NF];
#pragma unroll
    for (int m = 0; m < MF; ++m) {
      int row = wm + m * 16 + lr;
      af[m] = *(const bf16x8*)(smA[b] + row * 32 + ((lg ^ ((row >> 1) & 3)) << 3));
    }
#pragma unroll
    for (int n = 0; n < NF; ++n) {
      int row = wn + n * 16 + lr;
      bfr[n] = *(const bf16x8*)(smB[b] + row * 32 + ((lg ^ ((row >> 1) & 3)) << 3));
    }
    __builtin_amdgcn_s_setprio(1);
#pragma unroll
    for (int m = 0; m < MF; ++m)
#pragma unroll
      for (int n = 0; n < NF; ++n)
        acc[m][n] = __builtin_amdgcn_mfma_f32_16x16x32_bf16(af[m], bfr[n], acc[m][n], 0, 0, 0);
    __builtin_amdgcn_s_setprio(0);
    asm volatile("" ::: "memory");
    __builtin_amdgcn_s_barrier();
  }

#pragma unroll
  for (int m = 0; m < MF; ++m) {
    const int row = m0 + wm + m * 16 + lg * 4;
#pragma unroll
    for (int n = 0; n < NF; ++n) {
      const int col = n0 + wn + n * 16 + lr;
#pragma unroll
      for (int i = 0; i < 4; ++i) {
        float v = acc[m][n][i];
        size_t idx = (size_t)(row + i) * N + col;
        if constexpr (EPI == 0) {
          ((u16*)Cout)[idx] = f2bf(v + bias[col]);
        } else if constexpr (EPI == 2) {
          float cc = v + bias[col];
          float u = 0.7978845608f * (cc + 0.044715f * cc * cc * cc);
          float e = __expf(2.f * u);
          float th = 1.f - 2.f / (e + 1.f);
          ((u16*)Cout)[idx] = f2bf(0.5f * cc * (1.f + th));
        } else if constexpr (EPI == 4) {
          ((float*)Cout)[(size_t)blockIdx.z * M * N + idx] = v;
        } else {
          ((float*)Cout)[idx] = resid[idx] + gate[col] * (v + bias[col]);
        }
      }
    }
  }
}

// ---------------- combine 2 split-K partials: out = resid + gate*(p0+p1+bias) ----------------
__global__ __launch_bounds__(256)
void combine2(const float* __restrict__ part, const float* __restrict__ bias,
              const float* __restrict__ gate, const float* __restrict__ resid,
              float* __restrict__ out) {
  size_t idx = (size_t)blockIdx.x * 256 + threadIdx.x;   // over 2048*1024
  int col = (int)(idx & 1023);
  float v = part[idx] + part[(size_t)2048 * 1024 + idx] + bias[col];
  out[idx] = resid[idx] + gate[col] * v;
}

// ---------------- q/k: RMS norm + RoPE -> Q,K (h,pos,d) bf16 ----------------
// Q is pre-scaled by 1/8 (softmax scale folded here).
__global__ __launch_bounds__(256)
void qk_post(const u16* __restrict__ qkv_txt, const u16* __restrict__ qkv_img,
             const float* __restrict__ pe,
             const float* __restrict__ iq_s, const float* __restrict__ ik_s,
             const float* __restrict__ tq_s, const float* __restrict__ tk_s,
             u16* __restrict__ Q, u16* __restrict__ K) {
  const int d = threadIdx.x;                       // 0..63
  const int pos = blockIdx.x * 4 + threadIdx.y;    // 0..2303
  const int h = blockIdx.y;
  const u16* src; int r; const float *qs, *ks;
  if (pos < 256) { src = qkv_txt; r = pos; qs = tq_s; ks = tk_s; }
  else           { src = qkv_img; r = pos - 256; qs = iq_s; ks = ik_s; }
  float q = bf2f(src[(size_t)r * 3072 + h * 64 + d]);
  float k = bf2f(src[(size_t)r * 3072 + 1024 + h * 64 + d]);
  float qsq = q * q, ksq = k * k;
#pragma unroll
  for (int o = 32; o; o >>= 1) { qsq += __shfl_xor(qsq, o); ksq += __shfl_xor(ksq, o); }
  q *= rsqrtf(qsq * (1.f / 64.f) + 1e-6f) * qs[d];
  k *= rsqrtf(ksq * (1.f / 64.f) + 1e-6f) * ks[d];
  const int p = d >> 1, odd = d & 1;
  const float* pp = pe + (((size_t)pos * 32 + p) * 2 + odd) * 2;
  float qp = __shfl_xor(q, 1), kp = __shfl_xor(k, 1);
  float qe = odd ? qp : q, qo = odd ? q : qp;
  float ke = odd ? kp : k, ko = odd ? k : kp;
  float rq = pp[0] * qe + pp[1] * qo;
  float rk = pp[0] * ke + pp[1] * ko;
  size_t oidx = ((size_t)h * 2304 + pos) * 64 + d;
  Q[oidx] = f2bf(rq * 0.125f);
  K[oidx] = f2bf(rk);
}

// ---------------- V -> Vt (h, d, pos) bf16 ----------------
__global__ __launch_bounds__(512)
void v_transpose(const u16* __restrict__ qkv_txt, const u16* __restrict__ qkv_img,
                 u16* __restrict__ Vt) {
  __shared__ float tile[64][65];
  const int tx = threadIdx.x, ty = threadIdx.y;   // 64 x 8
  const int p0 = blockIdx.x * 64, h = blockIdx.y;
#pragma unroll
  for (int i = 0; i < 8; ++i) {
    int pos = p0 + ty + i * 8;
    const u16* src; int r;
    if (pos < 256) { src = qkv_txt; r = pos; } else { src = qkv_img; r = pos - 256; }
    tile[ty + i * 8][tx] = bf2f(src[(size_t)r * 3072 + 2048 + h * 64 + tx]);
  }
  __syncthreads();
#pragma unroll
  for (int i = 0; i < 8; ++i) {
    int d = ty + i * 8;
    Vt[((size_t)h * 64 + d) * 2304 + p0 + tx] = f2bf(tile[tx][d]);
  }
}

// ---------------- flash attention (split-KV, swapped QK^T) ----------------
__global__ __launch_bounds__(256, 3)
void attn_kernel(const u16* __restrict__ Q, const u16* __restrict__ Kb,
                 const u16* __restrict__ Vt,
                 float* __restrict__ Opart, float* __restrict__ ml) {
  __shared__ u16 smK[2][64 * 64];
  __shared__ u16 smV[2][64 * 64];
  __shared__ u16 smP[4 * 16 * 72];
  const int t = threadIdx.x, w = t >> 6, l = t & 63;
  const int lr = l & 15, lg = l >> 4;
  const int qt = blockIdx.x, h = blockIdx.y, sp = blockIdx.z;
  const int j0 = sp * 18;
  const u16* Qp = Q + ((size_t)h * 2304 + qt * 64 + w * 16 + lr) * 64;
  const bf16x8 qf0 = *(const bf16x8*)(Qp + lg * 8);
  const bf16x8 qf1 = *(const bf16x8*)(Qp + 32 + lg * 8);
  const u16* Kbase = Kb + (size_t)h * 2304 * 64;
  const u16* Vbase = Vt + (size_t)h * 64 * 2304;
  f32x4 accO[4] = {};
  float mrun = -1e30f, lrun = 0.f;
  u16* myP = smP + w * (16 * 72);

  const int c0 = w * 64 + l, c1 = c0 + 256;
  const int kr0 = c0 >> 3, ks0 = ((c0 & 7) ^ (kr0 & 7)) * 8;
  const int kr1 = c1 >> 3, ks1 = ((c1 & 7) ^ (kr1 & 7)) * 8;

  auto stage = [&](int j, int b) {
    const u16* gK = Kbase + (size_t)j * 64 * 64;
    GLDS16(gK + (size_t)kr0 * 64 + ks0, smK[b] + (w * 64) * 8);
    GLDS16(gK + (size_t)kr1 * 64 + ks1, smK[b] + (256 + w * 64) * 8);
    GLDS16(Vbase + (size_t)kr0 * 2304 + j * 64 + ks0, smV[b] + (w * 64) * 8);
    GLDS16(Vbase + (size_t)kr1 * 2304 + j * 64 + ks1, smV[b] + (256 + w * 64) * 8);
  };

  stage(j0, 0);
  for (int jj = 0; jj < 18; ++jj) {
    const int b = jj & 1;
    if (jj < 17) {
      stage(j0 + jj + 1, b ^ 1);
      asm volatile("s_waitcnt vmcnt(4)" ::: "memory");
    } else {
      asm volatile("s_waitcnt vmcnt(0)" ::: "memory");
    }
    __builtin_amdgcn_s_barrier();
    asm volatile("" ::: "memory");

    // S^T = K * Q^T : sf[n][i] = S[k = n*16+lg*4+i][q = lr]
    f32x4 sf[4];
    __builtin_amdgcn_s_setprio(1);
#pragma unroll
    for (int n = 0; n < 4; ++n) {
      const int row = n * 16 + lr, sw = row & 7;
      bf16x8 kf0 = *(const bf16x8*)(smK[b] + row * 64 + ((lg ^ sw) << 3));
      bf16x8 kf1 = *(const bf16x8*)(smK[b] + row * 64 + (((lg + 4) ^ sw) << 3));
      f32x4 z = {};
      z = __builtin_amdgcn_mfma_f32_16x16x32_bf16(kf0, qf0, z, 0, 0, 0);
      z = __builtin_amdgcn_mfma_f32_16x16x32_bf16(kf1, qf1, z, 0, 0, 0);
      sf[n] = z;
    }
    __builtin_amdgcn_s_setprio(0);

    float t0 = fmaxf(fmaxf(sf[0][0], sf[0][1]), fmaxf(sf[0][2], sf[0][3]));
    float t1 = fmaxf(fmaxf(sf[1][0], sf[1][1]), fmaxf(sf[1][2], sf[1][3]));
    float t2 = fmaxf(fmaxf(sf[2][0], sf[2][1]), fmaxf(sf[2][2], sf[2][3]));
    float t3 = fmaxf(fmaxf(sf[3][0], sf[3][1]), fmaxf(sf[3][2], sf[3][3]));
    float mx = fmaxf(fmaxf(t0, t1), fmaxf(t2, t3));
    mx = fmaxf(mx, __shfl_xor(mx, 16));
    mx = fmaxf(mx, __shfl_xor(mx, 32));
    const float mnew = fmaxf(mrun, mx);
    const float corr = __expf(mrun - mnew);
    mrun = mnew;

    float p[4][4];
#pragma unroll
    for (int n = 0; n < 4; ++n) {
      p[n][0] = __expf(sf[n][0] - mnew);
      p[n][1] = __expf(sf[n][1] - mnew);
      p[n][2] = __expf(sf[n][2] - mnew);
      p[n][3] = __expf(sf[n][3] - mnew);
    }
    float s0 = (p[0][0] + p[0][1]) + (p[0][2] + p[0][3]);
    float s1 = (p[1][0] + p[1][1]) + (p[1][2] + p[1][3]);
    float s2 = (p[2][0] + p[2][1]) + (p[2][2] + p[2][3]);
    float s3 = (p[3][0] + p[3][1]) + (p[3][2] + p[3][3]);
    float rs = (s0 + s1) + (s2 + s3);
    rs += __shfl_xor(rs, 16);
    rs += __shfl_xor(rs, 32);
    lrun = lrun * corr + rs;

#pragma unroll
    for (int n = 0; n < 4; ++n) {
      *(unsigned*)(myP + lr * 72 + n * 16 + lg * 4)     = cvt_pk_bf16(p[n][0], p[n][1]);
      *(unsigned*)(myP + lr * 72 + n * 16 + lg * 4 + 2) = cvt_pk_bf16(p[n][2], p[n][3]);
    }

    float cb[4];
#pragma unroll
    for (int i = 0; i < 4; ++i) cb[i] = __shfl(corr, lg * 4 + i);
#pragma unroll
    for (int nd = 0; nd < 4; ++nd)
#pragma unroll
      for (int i = 0; i < 4; ++i) accO[nd][i] *= cb[i];

    __builtin_amdgcn_s_setprio(1);
#pragma unroll
    for (int c = 0; c < 2; ++c) {
      bf16x8 pf = *(const bf16x8*)(myP + lr * 72 + c * 32 + lg * 8);
#pragma unroll
      for (int nd = 0; nd < 4; ++nd) {
        const int row = nd * 16 + lr, sw = row & 7;
        bf16x8 vf = *(const bf16x8*)(smV[b] + row * 64 + (((c * 4 + lg) ^ sw) << 3));
        accO[nd] = __builtin_amdgcn_mfma_f32_16x16x32_bf16(pf, vf, accO[nd], 0, 0, 0);
      }
    }
    __builtin_amdgcn_s_setprio(0);
    asm volatile("" ::: "memory");
    __builtin_amdgcn_s_barrier();
  }

  float* Op = Opart + (((size_t)(sp * 16 + h) * 2304) + qt * 64) * 64;
#pragma unroll
  for (int nd = 0; nd < 4; ++nd)
#pragma unroll
    for (int i = 0; i < 4; ++i)
      Op[(size_t)(w * 16 + lg * 4 + i) * 64 + nd * 16 + lr] = accO[nd][i];
  if (lg == 0) {
    size_t mi = ((size_t)(sp * 16 + h) * 2304 + qt * 64 + w * 16 + lr) * 2;
    ml[mi] = mrun;
    ml[mi + 1] = lrun;
  }
}

// ---------------- combine split-KV partials -> out (pos, h*64+d) bf16 ----------------
__global__ __launch_bounds__(256)
void attn_combine(const float* __restrict__ Opart, const float* __restrict__ ml,
                  u16* __restrict__ outb) {
  int idx = blockIdx.x * 256 + threadIdx.x;       // over 2304*1024
  int q = idx >> 10, c = idx & 1023;
  int h = c >> 6, d = c & 63;
  size_t i0 = (size_t)h * 2304 + q;
  size_t i1 = (size_t)(16 + h) * 2304 + q;
  float m0 = ml[i0 * 2], l0 = ml[i0 * 2 + 1];
  float m1 = ml[i1 * 2], l1 = ml[i1 * 2 + 1];
  float M = fmaxf(m0, m1);
  float w0 = __expf(m0 - M), w1 = __expf(m1 - M);
  float a0 = Opart[i0 * 64 + d], a1 = Opart[i1 * 64 + d];
  float num = w0 * a0 + w1 * a1;
  float den = w0 * l0 + w1 * l1;
  outb[(size_t)q * 1024 + c] = f2bf(num / den);
}

// ---------------- host ----------------
extern "C" void kernel_launch(void* const* d_in, const int* in_sizes, int n_in,
                              void* d_out, int out_size, void* d_ws, size_t ws_size,
                              hipStream_t stream) {
  const float* img         = (const float*)d_in[0];
  const float* txt         = (const float*)d_in[1];
  const float* pe          = (const float*)d_in[2];
  const float* vec         = (const float*)d_in[3];
  const float* img_mod_w   = (const float*)d_in[4];
  const float* img_mod_b   = (const float*)d_in[5];
  const float* txt_mod_w   = (const float*)d_in[6];
  const float* txt_mod_b   = (const float*)d_in[7];
  const float* img_qkv_w   = (const float*)d_in[8];
  const float* img_qkv_b   = (const float*)d_in[9];
  const float* img_q_scale = (const float*)d_in[10];
  const float* img_k_scale = (const float*)d_in[11];
  const float* img_proj_w  = (const float*)d_in[12];
  const float* img_proj_b  = (const float*)d_in[13];
  const float* txt_qkv_w   = (const float*)d_in[14];
  const float* txt_qkv_b   = (const float*)d_in[15];
  const float* txt_q_scale = (const float*)d_in[16];
  const float* txt_k_scale = (const float*)d_in[17];
  const float* mlp_w1      = (const float*)d_in[18];
  const float* mlp_b1      = (const float*)d_in[19];
  const float* mlp_w2      = (const float*)d_in[20];
  const float* mlp_b2      = (const float*)d_in[21];
  (void)in_sizes; (void)n_in; (void)out_size; (void)ws_size;

  char* ws = (char*)d_ws;
  size_t off = 0;
  auto alloc = [&](size_t bytes) -> void* {
    void* p = ws + off;
    off += (bytes + 255) & ~(size_t)255;
    return p;
  };
  float* sv     = (float*)alloc(1024 * 4);
  float* mod    = (float*)alloc(8192 * 4);
  // --- aliased region (18,874,368 B): {qkv_img, qkv_txt, img_m, txt_m}
  //     == Opart (attn partials, dead after attn_combine)
  //     == pml2  (mlp2 split-K partials, 16.8 MB, live only mlp2->combine2)
  u16* qkv_img  = (u16*)alloc((size_t)2048 * 3072 * 2);   // 12,582,912
  u16* qkv_txt  = (u16*)alloc((size_t)256 * 3072 * 2);    //  1,572,864
  u16* img_m    = (u16*)alloc((size_t)2048 * 1024 * 2);   //  4,194,304
  u16* txt_m    = (u16*)alloc((size_t)256 * 1024 * 2);    //    524,288
  float* Opart  = (float*)qkv_img;
  float* pml2   = (float*)qkv_img;
  float* mlbuf  = (float*)alloc((size_t)2 * 16 * 2304 * 2 * 4);
  u16* wt_iqkv  = (u16*)alloc((size_t)3072 * 1024 * 2);
  u16* wt_tqkv  = (u16*)alloc((size_t)3072 * 1024 * 2);
  u16* wt_proj  = (u16*)alloc((size_t)1024 * 1024 * 2);
  u16* wt_m1    = (u16*)alloc((size_t)4096 * 1024 * 2);
  u16* wt_m2    = (u16*)alloc((size_t)1024 * 4096 * 2);
  u16* Qb       = (u16*)alloc((size_t)16 * 2304 * 64 * 2);
  u16* Kb       = (u16*)alloc((size_t)16 * 2304 * 64 * 2);
  u16* Vtb      = (u16*)alloc((size_t)16 * 64 * 2304 * 2);
  u16* attnb    = (u16*)alloc((size_t)2304 * 1024 * 2);
  float* img2   = (float*)alloc((size_t)2048 * 1024 * 4);
  u16* h_in     = (u16*)alloc((size_t)2048 * 1024 * 2);
  u16* h1       = (u16*)alloc((size_t)2048 * 4096 * 2);

  const dim3 bT(32, 8);
  wconv_t<<<dim3(3072 / 32, 1024 / 32), bT, 0, stream>>>(img_qkv_w, wt_iqkv, 1024, 3072);
  wconv_t<<<dim3(3072 / 32, 1024 / 32), bT, 0, stream>>>(txt_qkv_w, wt_tqkv, 1024, 3072);
  wconv_t<<<dim3(1024 / 32, 1024 / 32), bT, 0, stream>>>(img_proj_w, wt_proj, 1024, 1024);
  wconv_t<<<dim3(4096 / 32, 1024 / 32), bT, 0, stream>>>(mlp_w1, wt_m1, 1024, 4096);
  wconv_t<<<dim3(1024 / 32, 4096 / 32), bT, 0, stream>>>(mlp_w2, wt_m2, 4096, 1024);

  silu_kernel<<<4, 256, 0, stream>>>(vec, sv);
  modinit<<<32, 256, 0, stream>>>(img_mod_b, txt_mod_b, mod);
  modgemv<<<dim3(32, 8), 256, 0, stream>>>(sv, img_mod_w, txt_mod_w, mod);

  ln_mod<<<2048, 256, 0, stream>>>(img, mod + 0, mod + 1024, img_m);
  ln_mod<<<256, 256, 0, stream>>>(txt, mod + 6144, mod + 7168, txt_m);

  gemm_bt<0, 128, 128><<<dim3(16, 24), 256, 0, stream>>>(img_m, wt_iqkv, 2048, 3072, 1024, 1024,
                                                         img_qkv_b, nullptr, nullptr, qkv_img);
  gemm_bt<0, 128, 128><<<dim3(2, 24), 256, 0, stream>>>(txt_m, wt_tqkv, 256, 3072, 1024, 1024,
                                                        txt_qkv_b, nullptr, nullptr, qkv_txt);

  qk_post<<<dim3(576, 16), dim3(64, 4), 0, stream>>>(qkv_txt, qkv_img, pe,
                                                     img_q_scale, img_k_scale,
                                                     txt_q_scale, txt_k_scale, Qb, Kb);
  v_transpose<<<dim3(36, 16), dim3(64, 8), 0, stream>>>(qkv_txt, qkv_img, Vtb);

  // qkv_img/qkv_txt/img_m/txt_m are dead past here; Opart aliases them.
  attn_kernel<<<dim3(36, 16, 2), 256, 0, stream>>>(Qb, Kb, Vtb, Opart, mlbuf);
  attn_combine<<<9216, 256, 0, stream>>>(Opart, mlbuf, attnb);

  gemm_bt<1, 64, 64><<<dim3(32, 16), 256, 0, stream>>>(attnb + (size_t)256 * 1024, wt_proj,
                                                       2048, 1024, 1024, 1024,
                                                       img_proj_b, mod + 2048, img, img2);
  ln_mod<<<2048, 256, 0, stream>>>(img2, mod + 3072, mod + 4096, h_in);
  gemm_bt<2, 128, 128><<<dim3(16, 32), 256, 0, stream>>>(h_in, wt_m1, 2048, 4096, 1024, 1024,
                                                         mlp_b1, nullptr, nullptr, h1);
  // mlp2: split-K x2 (Opart region is dead again), then fused combine -> d_out
  gemm_bt<4, 64, 64><<<dim3(32, 16, 2), 256, 0, stream>>>(h1, wt_m2, 2048, 1024, 4096, 2048,
                                                          nullptr, nullptr, nullptr, pml2);
  combine2<<<8192, 256, 0, stream>>>(pml2, mlp_b2, mod + 5120, img2, (float*)d_out);
}

// Round 9
// 405.770 us; speedup vs baseline: 1.2693x; 1.0151x over previous
//
#include <hip/hip_runtime.h>
#include <cstdint>
#include <cstddef>

typedef unsigned short u16;
typedef __attribute__((ext_vector_type(8))) short bf16x8;
typedef __attribute__((ext_vector_type(4))) float f32x4;

#define AS1 __attribute__((address_space(1)))
#define AS3 __attribute__((address_space(3)))
#define GLDS16(g, s) __builtin_amdgcn_global_load_lds((const AS1 void*)(g), (AS3 void*)(s), 16, 0, 0)

__device__ inline u16 f2bf(float f) {
  union { float f; unsigned u; } c; c.f = f;
  unsigned r = c.u + 0x7fffu + ((c.u >> 16) & 1u);
  return (u16)(r >> 16);
}
__device__ inline float bf2f(u16 s) {
  union { unsigned u; float f; } c; c.u = ((unsigned)s) << 16;
  return c.f;
}
__device__ inline unsigned cvt_pk_bf16(float a, float b) {
  unsigned r;
  asm("v_cvt_pk_bf16_f32 %0, %1, %2" : "=v"(r) : "v"(a), "v"(b));
  return r;
}

// ---------------- fused weight transpose/convert: 5 weights, one launch ----------------
// 32x32 tiles; segments hardcoded for this problem's shapes.
__global__ __launch_bounds__(256)
void wconv_all(const float* __restrict__ w_iqkv, const float* __restrict__ w_tqkv,
               const float* __restrict__ w_proj, const float* __restrict__ w_m1,
               const float* __restrict__ w_m2,
               u16* __restrict__ o_iqkv, u16* __restrict__ o_tqkv,
               u16* __restrict__ o_proj, u16* __restrict__ o_m1, u16* __restrict__ o_m2) {
  __shared__ float tile[32][33];
  const int tx = threadIdx.x, ty = threadIdx.y;
  int bid = blockIdx.x;
  const float* W; u16* Wt; int K, N, local;
  if (bid < 3072)       { W = w_iqkv; Wt = o_iqkv; K = 1024; N = 3072; local = bid; }
  else if (bid < 6144)  { W = w_tqkv; Wt = o_tqkv; K = 1024; N = 3072; local = bid - 3072; }
  else if (bid < 7168)  { W = w_proj; Wt = o_proj; K = 1024; N = 1024; local = bid - 6144; }
  else if (bid < 11264) { W = w_m1;   Wt = o_m1;   K = 1024; N = 4096; local = bid - 7168; }
  else                  { W = w_m2;   Wt = o_m2;   K = 4096; N = 1024; local = bid - 11264; }
  const int nb = N >> 5;
  const int n0 = (local % nb) * 32, k0 = (local / nb) * 32;
#pragma unroll
  for (int i = 0; i < 4; ++i)
    tile[ty + i * 8][tx] = W[(size_t)(k0 + ty + i * 8) * N + n0 + tx];
  __syncthreads();
#pragma unroll
  for (int i = 0; i < 4; ++i)
    Wt[(size_t)(n0 + ty + i * 8) * K + k0 + tx] = f2bf(tile[tx][ty + i * 8]);
}

// ---------------- modulation ----------------
__global__ __launch_bounds__(256)
void silu_kernel(const float* __restrict__ vec, float* __restrict__ sv) {
  int i = blockIdx.x * 256 + threadIdx.x;
  float x = vec[i];
  sv[i] = x / (1.f + __expf(-x));
}

__global__ __launch_bounds__(256)
void modinit(const float* __restrict__ imb, const float* __restrict__ tmb, float* __restrict__ mod) {
  int i = blockIdx.x * 256 + threadIdx.x;  // 8192
  mod[i] = (i < 6144) ? imb[i] : tmb[i - 6144];
}

__global__ __launch_bounds__(256)
void modgemv(const float* __restrict__ sv, const float* __restrict__ imw,
             const float* __restrict__ tmw, float* __restrict__ mod) {
  __shared__ float s[128];
  const int t = threadIdx.x;
  const int c = blockIdx.x * 256 + t;       // 0..8191
  const int kc = blockIdx.y * 128;          // k chunk
  if (t < 128) s[t] = sv[kc + t];
  __syncthreads();
  const float* W; int col;
  if (c < 6144) { W = imw; col = c; } else { W = tmw; col = c - 6144; }
  float acc = 0.f;
#pragma unroll 8
  for (int k = 0; k < 128; ++k) acc += s[k] * W[(size_t)(kc + k) * 6144 + col];
  atomicAdd(&mod[c], acc);
}

// ---------------- LayerNorm + modulate (img rows then txt rows) -> bf16 ----------------
__global__ __launch_bounds__(256)
void ln_mod2(const float* __restrict__ ximg, const float* __restrict__ xtxt,
             const float* __restrict__ mod, u16* __restrict__ oimg, u16* __restrict__ otxt) {
  const int row = blockIdx.x, t = threadIdx.x;
  const float* xr; const float *shift, *scale; u16* out; int r;
  if (row < 2048) { r = row; xr = ximg + (size_t)r * 1024; shift = mod;        scale = mod + 1024; out = oimg; }
  else            { r = row - 2048; xr = xtxt + (size_t)r * 1024; shift = mod + 6144; scale = mod + 7168; out = otxt; }
  float v[4], s = 0.f, sq = 0.f;
#pragma unroll
  for (int i = 0; i < 4; ++i) { v[i] = xr[t + i * 256]; s += v[i]; sq += v[i] * v[i]; }
#pragma unroll
  for (int o = 32; o; o >>= 1) { s += __shfl_down(s, o); sq += __shfl_down(sq, o); }
  __shared__ float ls[8];
  if ((t & 63) == 0) { ls[t >> 6] = s; ls[4 + (t >> 6)] = sq; }
  __syncthreads();
  s = ls[0] + ls[1] + ls[2] + ls[3];
  sq = ls[4] + ls[5] + ls[6] + ls[7];
  const float mean = s * (1.f / 1024.f);
  const float var = sq * (1.f / 1024.f) - mean * mean;
  const float rstd = rsqrtf(var + 1e-6f);
#pragma unroll
  for (int i = 0; i < 4; ++i) {
    int c = t + i * 256;
    float xn = (v[i] - mean) * rstd;
    out[(size_t)r * 1024 + c] = f2bf((1.f + scale[c]) * xn + shift[c]);
  }
}

// ---------------- GEMM: C = A(MxK)*Bt(NxK)^T, bf16, dbuf + swizzled LDS ----------------
// EPI 0: bf16 = acc+bias ; 1/3: f32 = resid+gate*(acc+bias) ; 2: bf16 = gelu(acc+bias)
// EPI 4: f32 partial (split-K, offset blockIdx.z*M*N, no bias)
template <int EPI, int BM, int BN>
__global__ __launch_bounds__(256, 3)
void gemm_bt(const u16* __restrict__ A, const u16* __restrict__ Bt,
             int M, int N, int Kstride, int Kspan,
             const float* __restrict__ bias, const float* __restrict__ gate,
             const float* __restrict__ resid, void* __restrict__ Cout) {
  constexpr int MF = BM / 32, NF = BN / 32, L = (BM + BN) / 64;
  __shared__ u16 smA[2][BM * 32];
  __shared__ u16 smB[2][BN * 32];
  const int t = threadIdx.x;
  const int w = t >> 6, l = t & 63;
  const int lr = l & 15, lg = l >> 4;
  const int m0 = blockIdx.x * BM, n0 = blockIdx.y * BN;
  const int koff = blockIdx.z * Kspan;
  const int wm = (w >> 1) * (BM / 2), wn = (w & 1) * (BN / 2);
  f32x4 acc[MF][NF] = {};

  const u16* gb[L];
  int doff[L];
  bool isA[L];
#pragma unroll
  for (int i = 0; i < L; ++i) {
    int c = t + i * 256;
    if (c < BM * 4) {
      int row = c >> 2, ch = c & 3;
      gb[i] = A + (size_t)(m0 + row) * Kstride + koff + ((ch ^ ((row >> 1) & 3)) << 3);
      doff[i] = c * 8; isA[i] = true;
    } else {
      int cc = c - BM * 4, row = cc >> 2, ch = cc & 3;
      gb[i] = Bt + (size_t)(n0 + row) * Kstride + koff + ((ch ^ ((row >> 1) & 3)) << 3);
      doff[i] = cc * 8; isA[i] = false;
    }
  }
  auto stage = [&](int kt, int b) {
#pragma unroll
    for (int i = 0; i < L; ++i)
      GLDS16(gb[i] + (kt << 5), (isA[i] ? smA[b] : smB[b]) + doff[i]);
  };

  const int nk = Kspan >> 5;
  stage(0, 0);
  for (int kt = 0; kt < nk; ++kt) {
    const int b = kt & 1;
    if (kt < nk - 1) {
      stage(kt + 1, b ^ 1);
      if constexpr (L == 4)      asm volatile("s_waitcnt vmcnt(4)" ::: "memory");
      else if constexpr (L == 3) asm volatile("s_waitcnt vmcnt(3)" ::: "memory");
      else                       asm volatile("s_waitcnt vmcnt(2)" ::: "memory");
    } else {
      asm volatile("s_waitcnt vmcnt(0)" ::: "memory");
    }
    __builtin_amdgcn_s_barrier();
    asm volatile("" ::: "memory");

    bf16x8 af[MF], bfr[NF];
#pragma unroll
    for (int m = 0; m < MF; ++m) {
      int row = wm + m * 16 + lr;
      af[m] = *(const bf16x8*)(smA[b] + row * 32 + ((lg ^ ((row >> 1) & 3)) << 3));
    }
#pragma unroll
    for (int n = 0; n < NF; ++n) {
      int row = wn + n * 16 + lr;
      bfr[n] = *(const bf16x8*)(smB[b] + row * 32 + ((lg ^ ((row >> 1) & 3)) << 3));
    }
    __builtin_amdgcn_s_setprio(1);
#pragma unroll
    for (int m = 0; m < MF; ++m)
#pragma unroll
      for (int n = 0; n < NF; ++n)
        acc[m][n] = __builtin_amdgcn_mfma_f32_16x16x32_bf16(af[m], bfr[n], acc[m][n], 0, 0, 0);
    __builtin_amdgcn_s_setprio(0);
    asm volatile("" ::: "memory");
    __builtin_amdgcn_s_barrier();
  }

#pragma unroll
  for (int m = 0; m < MF; ++m) {
    const int row = m0 + wm + m * 16 + lg * 4;
#pragma unroll
    for (int n = 0; n < NF; ++n) {
      const int col = n0 + wn + n * 16 + lr;
#pragma unroll
      for (int i = 0; i < 4; ++i) {
        float v = acc[m][n][i];
        size_t idx = (size_t)(row + i) * N + col;
        if constexpr (EPI == 0) {
          ((u16*)Cout)[idx] = f2bf(v + bias[col]);
        } else if constexpr (EPI == 2) {
          float cc = v + bias[col];
          float u = 0.7978845608f * (cc + 0.044715f * cc * cc * cc);
          float e = __expf(2.f * u);
          float th = 1.f - 2.f / (e + 1.f);
          ((u16*)Cout)[idx] = f2bf(0.5f * cc * (1.f + th));
        } else if constexpr (EPI == 4) {
          ((float*)Cout)[(size_t)blockIdx.z * M * N + idx] = v;
        } else {
          ((float*)Cout)[idx] = resid[idx] + gate[col] * (v + bias[col]);
        }
      }
    }
  }
}

// ---------------- combine 2 split-K partials: out = resid + gate*(p0+p1+bias) ----------------
__global__ __launch_bounds__(256)
void combine2(const float* __restrict__ part, const float* __restrict__ bias,
              const float* __restrict__ gate, const float* __restrict__ resid,
              float* __restrict__ out) {
  size_t idx = (size_t)blockIdx.x * 256 + threadIdx.x;   // over 2048*1024
  int col = (int)(idx & 1023);
  float v = part[idx] + part[(size_t)2048 * 1024 + idx] + bias[col];
  out[idx] = resid[idx] + gate[col] * v;
}

// ---------------- q/k: RMS norm + RoPE -> Q,K (h,pos,d) bf16 ----------------
// Q pre-scaled by (1/8)*log2(e): attention softmax runs in exp2 domain.
__global__ __launch_bounds__(256)
void qk_post(const u16* __restrict__ qkv_txt, const u16* __restrict__ qkv_img,
             const float* __restrict__ pe,
             const float* __restrict__ iq_s, const float* __restrict__ ik_s,
             const float* __restrict__ tq_s, const float* __restrict__ tk_s,
             u16* __restrict__ Q, u16* __restrict__ K) {
  const int d = threadIdx.x;                       // 0..63
  const int pos = blockIdx.x * 4 + threadIdx.y;    // 0..2303
  const int h = blockIdx.y;
  const u16* src; int r; const float *qs, *ks;
  if (pos < 256) { src = qkv_txt; r = pos; qs = tq_s; ks = tk_s; }
  else           { src = qkv_img; r = pos - 256; qs = iq_s; ks = ik_s; }
  float q = bf2f(src[(size_t)r * 3072 + h * 64 + d]);
  float k = bf2f(src[(size_t)r * 3072 + 1024 + h * 64 + d]);
  float qsq = q * q, ksq = k * k;
#pragma unroll
  for (int o = 32; o; o >>= 1) { qsq += __shfl_xor(qsq, o); ksq += __shfl_xor(ksq, o); }
  q *= rsqrtf(qsq * (1.f / 64.f) + 1e-6f) * qs[d];
  k *= rsqrtf(ksq * (1.f / 64.f) + 1e-6f) * ks[d];
  const int p = d >> 1, odd = d & 1;
  const float* pp = pe + (((size_t)pos * 32 + p) * 2 + odd) * 2;
  float qp = __shfl_xor(q, 1), kp = __shfl_xor(k, 1);
  float qe = odd ? qp : q, qo = odd ? q : qp;
  float ke = odd ? kp : k, ko = odd ? k : kp;
  float rq = pp[0] * qe + pp[1] * qo;
  float rk = pp[0] * ke + pp[1] * ko;
  size_t oidx = ((size_t)h * 2304 + pos) * 64 + d;
  Q[oidx] = f2bf(rq * 0.1803368801111204f);   // 0.125 * log2(e)
  K[oidx] = f2bf(rk);
}

// ---------------- V -> Vt (h, d, pos) bf16 ----------------
__global__ __launch_bounds__(512)
void v_transpose(const u16* __restrict__ qkv_txt, const u16* __restrict__ qkv_img,
                 u16* __restrict__ Vt) {
  __shared__ float tile[64][65];
  const int tx = threadIdx.x, ty = threadIdx.y;   // 64 x 8
  const int p0 = blockIdx.x * 64, h = blockIdx.y;
#pragma unroll
  for (int i = 0; i < 8; ++i) {
    int pos = p0 + ty + i * 8;
    const u16* src; int r;
    if (pos < 256) { src = qkv_txt; r = pos; } else { src = qkv_img; r = pos - 256; }
    tile[ty + i * 8][tx] = bf2f(src[(size_t)r * 3072 + 2048 + h * 64 + tx]);
  }
  __syncthreads();
#pragma unroll
  for (int i = 0; i < 8; ++i) {
    int d = ty + i * 8;
    Vt[((size_t)h * 64 + d) * 2304 + p0 + tx] = f2bf(tile[tx][d]);
  }
}

// ---------------- flash attention (split-KV, swapped QK^T, exp2 domain) ----------------
// LDS exactly 40 KB -> 4 blocks/CU. smP: per-wave 16x64 u16, XOR-chunk swizzled.
__global__ __launch_bounds__(256, 4)
void attn_kernel(const u16* __restrict__ Q, const u16* __restrict__ Kb,
                 const u16* __restrict__ Vt,
                 float* __restrict__ Opart, float* __restrict__ ml) {
  __shared__ u16 smK[2][64 * 64];
  __shared__ u16 smV[2][64 * 64];
  __shared__ u16 smP[4][16 * 64];
  const int t = threadIdx.x, w = t >> 6, l = t & 63;
  const int lr = l & 15, lg = l >> 4;
  const int qt = blockIdx.x, h = blockIdx.y, sp = blockIdx.z;
  const int j0 = sp * 18;
  const u16* Qp = Q + ((size_t)h * 2304 + qt * 64 + w * 16 + lr) * 64;
  const bf16x8 qf0 = *(const bf16x8*)(Qp + lg * 8);
  const bf16x8 qf1 = *(const bf16x8*)(Qp + 32 + lg * 8);
  const u16* Kbase = Kb + (size_t)h * 2304 * 64;
  const u16* Vbase = Vt + (size_t)h * 64 * 2304;
  f32x4 accO[4] = {};
  float mrun = -1e30f, lrun = 0.f;
  u16* myP = smP[w];

  const int c0 = w * 64 + l, c1 = c0 + 256;
  const int kr0 = c0 >> 3, ks0 = ((c0 & 7) ^ (kr0 & 7)) * 8;
  const int kr1 = c1 >> 3, ks1 = ((c1 & 7) ^ (kr1 & 7)) * 8;

  auto stage = [&](int j, int b) {
    const u16* gK = Kbase + (size_t)j * 64 * 64;
    GLDS16(gK + (size_t)kr0 * 64 + ks0, smK[b] + (w * 64) * 8);
    GLDS16(gK + (size_t)kr1 * 64 + ks1, smK[b] + (256 + w * 64) * 8);
    GLDS16(Vbase + (size_t)kr0 * 2304 + j * 64 + ks0, smV[b] + (w * 64) * 8);
    GLDS16(Vbase + (size_t)kr1 * 2304 + j * 64 + ks1, smV[b] + (256 + w * 64) * 8);
  };

  stage(j0, 0);
  for (int jj = 0; jj < 18; ++jj) {
    const int b = jj & 1;
    if (jj < 17) {
      stage(j0 + jj + 1, b ^ 1);
      asm volatile("s_waitcnt vmcnt(4)" ::: "memory");
    } else {
      asm volatile("s_waitcnt vmcnt(0)" ::: "memory");
    }
    __builtin_amdgcn_s_barrier();
    asm volatile("" ::: "memory");

    // S^T = K * Q^T (log2 domain): sf[n][i] = S[k = n*16+lg*4+i][q = lr]
    f32x4 sf[4];
    __builtin_amdgcn_s_setprio(1);
#pragma unroll
    for (int n = 0; n < 4; ++n) {
      const int row = n * 16 + lr, sw = row & 7;
      bf16x8 kf0 = *(const bf16x8*)(smK[b] + row * 64 + ((lg ^ sw) << 3));
      bf16x8 kf1 = *(const bf16x8*)(smK[b] + row * 64 + (((lg + 4) ^ sw) << 3));
      f32x4 z = {};
      z = __builtin_amdgcn_mfma_f32_16x16x32_bf16(kf0, qf0, z, 0, 0, 0);
      z = __builtin_amdgcn_mfma_f32_16x16x32_bf16(kf1, qf1, z, 0, 0, 0);
      sf[n] = z;
    }
    __builtin_amdgcn_s_setprio(0);

    float t0 = fmaxf(fmaxf(sf[0][0], sf[0][1]), fmaxf(sf[0][2], sf[0][3]));
    float t1 = fmaxf(fmaxf(sf[1][0], sf[1][1]), fmaxf(sf[1][2], sf[1][3]));
    float t2 = fmaxf(fmaxf(sf[2][0], sf[2][1]), fmaxf(sf[2][2], sf[2][3]));
    float t3 = fmaxf(fmaxf(sf[3][0], sf[3][1]), fmaxf(sf[3][2], sf[3][3]));
    float mx = fmaxf(fmaxf(t0, t1), fmaxf(t2, t3));
    mx = fmaxf(mx, __shfl_xor(mx, 16));
    mx = fmaxf(mx, __shfl_xor(mx, 32));
    const float mnew = fmaxf(mrun, mx);
    const float corr = exp2f(mrun - mnew);
    mrun = mnew;

    float p[4][4];
#pragma unroll
    for (int n = 0; n < 4; ++n) {
      p[n][0] = exp2f(sf[n][0] - mnew);
      p[n][1] = exp2f(sf[n][1] - mnew);
      p[n][2] = exp2f(sf[n][2] - mnew);
      p[n][3] = exp2f(sf[n][3] - mnew);
    }
    float s0 = (p[0][0] + p[0][1]) + (p[0][2] + p[0][3]);
    float s1 = (p[1][0] + p[1][1]) + (p[1][2] + p[1][3]);
    float s2 = (p[2][0] + p[2][1]) + (p[2][2] + p[2][3]);
    float s3 = (p[3][0] + p[3][1]) + (p[3][2] + p[3][3]);
    float rs = (s0 + s1) + (s2 + s3);
    rs += __shfl_xor(rs, 16);
    rs += __shfl_xor(rs, 32);
    lrun = lrun * corr + rs;

    // P store into swizzled 16x64 tile: element P[q=lr][k], chunk = k>>3,
    // swizzled chunk' = chunk ^ (lr&7). Write b32 pairs.
#pragma unroll
    for (int n = 0; n < 4; ++n) {
      const int cA = (2 * n + (lg >> 1)) ^ (lr & 7);
      u16* base = myP + lr * 64 + cA * 8 + (lg & 1) * 4;
      *(unsigned*)(base)     = cvt_pk_bf16(p[n][0], p[n][1]);
      *(unsigned*)(base + 2) = cvt_pk_bf16(p[n][2], p[n][3]);
    }

    float cb[4];
#pragma unroll
    for (int i = 0; i < 4; ++i) cb[i] = __shfl(corr, lg * 4 + i);
#pragma unroll
    for (int nd = 0; nd < 4; ++nd)
#pragma unroll
      for (int i = 0; i < 4; ++i) accO[nd][i] *= cb[i];

    // PV: A-frag = P[q=lr][k = c*32+lg*8 ..+8] -> chunk 4c+lg, swizzled ^(lr&7)
    __builtin_amdgcn_s_setprio(1);
#pragma unroll
    for (int c = 0; c < 2; ++c) {
      bf16x8 pf = *(const bf16x8*)(myP + lr * 64 + (((4 * c + lg) ^ (lr & 7)) << 3));
#pragma unroll
      for (int nd = 0; nd < 4; ++nd) {
        const int row = nd * 16 + lr, sw = row & 7;
        bf16x8 vf = *(const bf16x8*)(smV[b] + row * 64 + (((c * 4 + lg) ^ sw) << 3));
        accO[nd] = __builtin_amdgcn_mfma_f32_16x16x32_bf16(pf, vf, accO[nd], 0, 0, 0);
      }
    }
    __builtin_amdgcn_s_setprio(0);
    asm volatile("" ::: "memory");
    __builtin_amdgcn_s_barrier();
  }

  float* Op = Opart + (((size_t)(sp * 16 + h) * 2304) + qt * 64) * 64;
#pragma unroll
  for (int nd = 0; nd < 4; ++nd)
#pragma unroll
    for (int i = 0; i < 4; ++i)
      Op[(size_t)(w * 16 + lg * 4 + i) * 64 + nd * 16 + lr] = accO[nd][i];
  if (lg == 0) {
    size_t mi = ((size_t)(sp * 16 + h) * 2304 + qt * 64 + w * 16 + lr) * 2;
    ml[mi] = mrun;
    ml[mi + 1] = lrun;
  }
}

// ---------------- combine split-KV partials -> out (pos, h*64+d) bf16 ----------------
__global__ __launch_bounds__(256)
void attn_combine(const float* __restrict__ Opart, const float* __restrict__ ml,
                  u16* __restrict__ outb) {
  int idx = blockIdx.x * 256 + threadIdx.x;       // over 2304*1024
  int q = idx >> 10, c = idx & 1023;
  int h = c >> 6, d = c & 63;
  size_t i0 = (size_t)h * 2304 + q;
  size_t i1 = (size_t)(16 + h) * 2304 + q;
  float m0 = ml[i0 * 2], l0 = ml[i0 * 2 + 1];
  float m1 = ml[i1 * 2], l1 = ml[i1 * 2 + 1];
  float M = fmaxf(m0, m1);
  float w0 = exp2f(m0 - M), w1 = exp2f(m1 - M);
  float a0 = Opart[i0 * 64 + d], a1 = Opart[i1 * 64 + d];
  float num = w0 * a0 + w1 * a1;
  float den = w0 * l0 + w1 * l1;
  outb[(size_t)q * 1024 + c] = f2bf(num / den);
}

// ---------------- host ----------------
extern "C" void kernel_launch(void* const* d_in, const int* in_sizes, int n_in,
                              void* d_out, int out_size, void* d_ws, size_t ws_size,
                              hipStream_t stream) {
  const float* img         = (const float*)d_in[0];
  const float* txt         = (const float*)d_in[1];
  const float* pe          = (const float*)d_in[2];
  const float* vec         = (const float*)d_in[3];
  const float* img_mod_w   = (const float*)d_in[4];
  const float* img_mod_b   = (const float*)d_in[5];
  const float* txt_mod_w   = (const float*)d_in[6];
  const float* txt_mod_b   = (const float*)d_in[7];
  const float* img_qkv_w   = (const float*)d_in[8];
  const float* img_qkv_b   = (const float*)d_in[9];
  const float* img_q_scale = (const float*)d_in[10];
  const float* img_k_scale = (const float*)d_in[11];
  const float* img_proj_w  = (const float*)d_in[12];
  const float* img_proj_b  = (const float*)d_in[13];
  const float* txt_qkv_w   = (const float*)d_in[14];
  const float* txt_qkv_b   = (const float*)d_in[15];
  const float* txt_q_scale = (const float*)d_in[16];
  const float* txt_k_scale = (const float*)d_in[17];
  const float* mlp_w1      = (const float*)d_in[18];
  const float* mlp_b1      = (const float*)d_in[19];
  const float* mlp_w2      = (const float*)d_in[20];
  const float* mlp_b2      = (const float*)d_in[21];
  (void)in_sizes; (void)n_in; (void)out_size; (void)ws_size;

  char* ws = (char*)d_ws;
  size_t off = 0;
  auto alloc = [&](size_t bytes) -> void* {
    void* p = ws + off;
    off += (bytes + 255) & ~(size_t)255;
    return p;
  };
  float* sv     = (float*)alloc(1024 * 4);
  float* mod    = (float*)alloc(8192 * 4);
  // --- aliased region (18,874,368 B): {qkv_img, qkv_txt, img_m, txt_m}
  //     == Opart (attn partials) == pml2 (mlp2 split-K partials)
  u16* qkv_img  = (u16*)alloc((size_t)2048 * 3072 * 2);
  u16* qkv_txt  = (u16*)alloc((size_t)256 * 3072 * 2);
  u16* img_m    = (u16*)alloc((size_t)2048 * 1024 * 2);
  u16* txt_m    = (u16*)alloc((size_t)256 * 1024 * 2);
  float* Opart  = (float*)qkv_img;
  float* pml2   = (float*)qkv_img;
  float* mlbuf  = (float*)alloc((size_t)2 * 16 * 2304 * 2 * 4);
  u16* wt_iqkv  = (u16*)alloc((size_t)3072 * 1024 * 2);
  u16* wt_tqkv  = (u16*)alloc((size_t)3072 * 1024 * 2);
  u16* wt_proj  = (u16*)alloc((size_t)1024 * 1024 * 2);
  u16* wt_m1    = (u16*)alloc((size_t)4096 * 1024 * 2);
  u16* wt_m2    = (u16*)alloc((size_t)1024 * 4096 * 2);
  u16* Qb       = (u16*)alloc((size_t)16 * 2304 * 64 * 2);
  u16* Kb       = (u16*)alloc((size_t)16 * 2304 * 64 * 2);
  u16* Vtb      = (u16*)alloc((size_t)16 * 64 * 2304 * 2);
  u16* attnb    = (u16*)alloc((size_t)2304 * 1024 * 2);
  float* img2   = (float*)alloc((size_t)2048 * 1024 * 4);
  u16* h_in     = (u16*)alloc((size_t)2048 * 1024 * 2);
  u16* h1       = (u16*)alloc((size_t)2048 * 4096 * 2);

  wconv_all<<<15360, dim3(32, 8), 0, stream>>>(img_qkv_w, txt_qkv_w, img_proj_w, mlp_w1, mlp_w2,
                                               wt_iqkv, wt_tqkv, wt_proj, wt_m1, wt_m2);

  silu_kernel<<<4, 256, 0, stream>>>(vec, sv);
  modinit<<<32, 256, 0, stream>>>(img_mod_b, txt_mod_b, mod);
  modgemv<<<dim3(32, 8), 256, 0, stream>>>(sv, img_mod_w, txt_mod_w, mod);

  ln_mod2<<<2304, 256, 0, stream>>>(img, txt, mod, img_m, txt_m);

  gemm_bt<0, 64, 128><<<dim3(32, 24), 256, 0, stream>>>(img_m, wt_iqkv, 2048, 3072, 1024, 1024,
                                                        img_qkv_b, nullptr, nullptr, qkv_img);
  gemm_bt<0, 64, 128><<<dim3(4, 24), 256, 0, stream>>>(txt_m, wt_tqkv, 256, 3072, 1024, 1024,
                                                       txt_qkv_b, nullptr, nullptr, qkv_txt);

  qk_post<<<dim3(576, 16), dim3(64, 4), 0, stream>>>(qkv_txt, qkv_img, pe,
                                                     img_q_scale, img_k_scale,
                                                     txt_q_scale, txt_k_scale, Qb, Kb);
  v_transpose<<<dim3(36, 16), dim3(64, 8), 0, stream>>>(qkv_txt, qkv_img, Vtb);

  // qkv_img/qkv_txt/img_m/txt_m are dead past here; Opart aliases them.
  attn_kernel<<<dim3(36, 16, 2), 256, 0, stream>>>(Qb, Kb, Vtb, Opart, mlbuf);
  attn_combine<<<9216, 256, 0, stream>>>(Opart, mlbuf, attnb);

  gemm_bt<1, 64, 64><<<dim3(32, 16), 256, 0, stream>>>(attnb + (size_t)256 * 1024, wt_proj,
                                                       2048, 1024, 1024, 1024,
                                                       img_proj_b, mod + 2048, img, img2);
  ln_mod2<<<2048, 256, 0, stream>>>(img2, nullptr, mod + 3072, h_in, nullptr);
  gemm_bt<2, 64, 128><<<dim3(32, 32), 256, 0, stream>>>(h_in, wt_m1, 2048, 4096, 1024, 1024,
                                                        mlp_b1, nullptr, nullptr, h1);
  gemm_bt<4, 64, 64><<<dim3(32, 16, 2), 256, 0, stream>>>(h1, wt_m2, 2048, 1024, 4096, 2048,
                                                          nullptr, nullptr, nullptr, pml2);
  combine2<<<8192, 256, 0, stream>>>(pml2, mlp_b2, mod + 5120, img2, (float*)d_out);
}

// Round 10
// 405.456 us; speedup vs baseline: 1.2703x; 1.0008x over previous
//
#include <hip/hip_runtime.h>
#include <cstdint>
#include <cstddef>

typedef unsigned short u16;
typedef __attribute__((ext_vector_type(8))) short bf16x8;
typedef __attribute__((ext_vector_type(4))) float f32x4;

#define AS1 __attribute__((address_space(1)))
#define AS3 __attribute__((address_space(3)))
#define GLDS16(g, s) __builtin_amdgcn_global_load_lds((const AS1 void*)(g), (AS3 void*)(s), 16, 0, 0)

__device__ inline u16 f2bf(float f) {
  union { float f; unsigned u; } c; c.f = f;
  unsigned r = c.u + 0x7fffu + ((c.u >> 16) & 1u);
  return (u16)(r >> 16);
}
__device__ inline float bf2f(u16 s) {
  union { unsigned u; float f; } c; c.u = ((unsigned)s) << 16;
  return c.f;
}
__device__ inline unsigned cvt_pk_bf16(float a, float b) {
  unsigned r;
  asm("v_cvt_pk_bf16_f32 %0, %1, %2" : "=v"(r) : "v"(a), "v"(b));
  return r;
}

// ---------------- fused weight transpose/convert: 5 weights, one launch ----------------
__global__ __launch_bounds__(256)
void wconv_all(const float* __restrict__ w_iqkv, const float* __restrict__ w_tqkv,
               const float* __restrict__ w_proj, const float* __restrict__ w_m1,
               const float* __restrict__ w_m2,
               u16* __restrict__ o_iqkv, u16* __restrict__ o_tqkv,
               u16* __restrict__ o_proj, u16* __restrict__ o_m1, u16* __restrict__ o_m2) {
  __shared__ float tile[32][33];
  const int tx = threadIdx.x, ty = threadIdx.y;
  int bid = blockIdx.x;
  const float* W; u16* Wt; int K, N, local;
  if (bid < 3072)       { W = w_iqkv; Wt = o_iqkv; K = 1024; N = 3072; local = bid; }
  else if (bid < 6144)  { W = w_tqkv; Wt = o_tqkv; K = 1024; N = 3072; local = bid - 3072; }
  else if (bid < 7168)  { W = w_proj; Wt = o_proj; K = 1024; N = 1024; local = bid - 6144; }
  else if (bid < 11264) { W = w_m1;   Wt = o_m1;   K = 1024; N = 4096; local = bid - 7168; }
  else                  { W = w_m2;   Wt = o_m2;   K = 4096; N = 1024; local = bid - 11264; }
  const int nb = N >> 5;
  const int n0 = (local % nb) * 32, k0 = (local / nb) * 32;
#pragma unroll
  for (int i = 0; i < 4; ++i)
    tile[ty + i * 8][tx] = W[(size_t)(k0 + ty + i * 8) * N + n0 + tx];
  __syncthreads();
#pragma unroll
  for (int i = 0; i < 4; ++i)
    Wt[(size_t)(n0 + ty + i * 8) * K + k0 + tx] = f2bf(tile[tx][ty + i * 8]);
}

// ---------------- modulation ----------------
__global__ __launch_bounds__(256)
void silu_kernel(const float* __restrict__ vec, float* __restrict__ sv) {
  int i = blockIdx.x * 256 + threadIdx.x;
  float x = vec[i];
  sv[i] = x / (1.f + __expf(-x));
}

__global__ __launch_bounds__(256)
void modinit(const float* __restrict__ imb, const float* __restrict__ tmb, float* __restrict__ mod) {
  int i = blockIdx.x * 256 + threadIdx.x;  // 8192
  mod[i] = (i < 6144) ? imb[i] : tmb[i - 6144];
}

__global__ __launch_bounds__(256)
void modgemv(const float* __restrict__ sv, const float* __restrict__ imw,
             const float* __restrict__ tmw, float* __restrict__ mod) {
  __shared__ float s[128];
  const int t = threadIdx.x;
  const int c = blockIdx.x * 256 + t;       // 0..8191
  const int kc = blockIdx.y * 128;          // k chunk
  if (t < 128) s[t] = sv[kc + t];
  __syncthreads();
  const float* W; int col;
  if (c < 6144) { W = imw; col = c; } else { W = tmw; col = c - 6144; }
  float acc = 0.f;
#pragma unroll 8
  for (int k = 0; k < 128; ++k) acc += s[k] * W[(size_t)(kc + k) * 6144 + col];
  atomicAdd(&mod[c], acc);
}

// ---------------- LayerNorm + modulate (img rows then txt rows) -> bf16 ----------------
__global__ __launch_bounds__(256)
void ln_mod2(const float* __restrict__ ximg, const float* __restrict__ xtxt,
             const float* __restrict__ mod, u16* __restrict__ oimg, u16* __restrict__ otxt) {
  const int row = blockIdx.x, t = threadIdx.x;
  const float* xr; const float *shift, *scale; u16* out; int r;
  if (row < 2048) { r = row; xr = ximg + (size_t)r * 1024; shift = mod;        scale = mod + 1024; out = oimg; }
  else            { r = row - 2048; xr = xtxt + (size_t)r * 1024; shift = mod + 6144; scale = mod + 7168; out = otxt; }
  float v[4], s = 0.f, sq = 0.f;
#pragma unroll
  for (int i = 0; i < 4; ++i) { v[i] = xr[t + i * 256]; s += v[i]; sq += v[i] * v[i]; }
#pragma unroll
  for (int o = 32; o; o >>= 1) { s += __shfl_down(s, o); sq += __shfl_down(sq, o); }
  __shared__ float ls[8];
  if ((t & 63) == 0) { ls[t >> 6] = s; ls[4 + (t >> 6)] = sq; }
  __syncthreads();
  s = ls[0] + ls[1] + ls[2] + ls[3];
  sq = ls[4] + ls[5] + ls[6] + ls[7];
  const float mean = s * (1.f / 1024.f);
  const float var = sq * (1.f / 1024.f) - mean * mean;
  const float rstd = rsqrtf(var + 1e-6f);
#pragma unroll
  for (int i = 0; i < 4; ++i) {
    int c = t + i * 256;
    float xn = (v[i] - mean) * rstd;
    out[(size_t)r * 1024 + c] = f2bf((1.f + scale[c]) * xn + shift[c]);
  }
}

// ---------------- GEMM: C = A(MxK)*Bt(NxK)^T, bf16, dbuf + swizzled LDS ----------------
// EPI 0: bf16 = acc+bias ; 1/3: f32 = resid+gate*(acc+bias) ; 2: bf16 = gelu(acc+bias)
// EPI 4: f32 partial (split-K, offset blockIdx.z*M*N, no bias)
template <int EPI, int BM, int BN>
__global__ __launch_bounds__(256, 3)
void gemm_bt(const u16* __restrict__ A, const u16* __restrict__ Bt,
             int M, int N, int Kstride, int Kspan,
             const float* __restrict__ bias, const float* __restrict__ gate,
             const float* __restrict__ resid, void* __restrict__ Cout) {
  constexpr int MF = BM / 32, NF = BN / 32, L = (BM + BN) / 64;
  __shared__ u16 smA[2][BM * 32];
  __shared__ u16 smB[2][BN * 32];
  const int t = threadIdx.x;
  const int w = t >> 6, l = t & 63;
  const int lr = l & 15, lg = l >> 4;
  const int m0 = blockIdx.x * BM, n0 = blockIdx.y * BN;
  const int koff = blockIdx.z * Kspan;
  const int wm = (w >> 1) * (BM / 2), wn = (w & 1) * (BN / 2);
  f32x4 acc[MF][NF] = {};

  const u16* gb[L];
  int doff[L];
  bool isA[L];
#pragma unroll
  for (int i = 0; i < L; ++i) {
    int c = t + i * 256;
    if (c < BM * 4) {
      int row = c >> 2, ch = c & 3;
      gb[i] = A + (size_t)(m0 + row) * Kstride + koff + ((ch ^ ((row >> 1) & 3)) << 3);
      doff[i] = c * 8; isA[i] = true;
    } else {
      int cc = c - BM * 4, row = cc >> 2, ch = cc & 3;
      gb[i] = Bt + (size_t)(n0 + row) * Kstride + koff + ((ch ^ ((row >> 1) & 3)) << 3);
      doff[i] = cc * 8; isA[i] = false;
    }
  }
  auto stage = [&](int kt, int b) {
#pragma unroll
    for (int i = 0; i < L; ++i)
      GLDS16(gb[i] + (kt << 5), (isA[i] ? smA[b] : smB[b]) + doff[i]);
  };

  const int nk = Kspan >> 5;
  stage(0, 0);
  for (int kt = 0; kt < nk; ++kt) {
    const int b = kt & 1;
    if (kt < nk - 1) {
      stage(kt + 1, b ^ 1);
      if constexpr (L == 4)      asm volatile("s_waitcnt vmcnt(4)" ::: "memory");
      else if constexpr (L == 3) asm volatile("s_waitcnt vmcnt(3)" ::: "memory");
      else                       asm volatile("s_waitcnt vmcnt(2)" ::: "memory");
    } else {
      asm volatile("s_waitcnt vmcnt(0)" ::: "memory");
    }
    __builtin_amdgcn_s_barrier();
    asm volatile("" ::: "memory");

    bf16x8 af[MF], bfr[NF];
#pragma unroll
    for (int m = 0; m < MF; ++m) {
      int row = wm + m * 16 + lr;
      af[m] = *(const bf16x8*)(smA[b] + row * 32 + ((lg ^ ((row >> 1) & 3)) << 3));
    }
#pragma unroll
    for (int n = 0; n < NF; ++n) {
      int row = wn + n * 16 + lr;
      bfr[n] = *(const bf16x8*)(smB[b] + row * 32 + ((lg ^ ((row >> 1) & 3)) << 3));
    }
    __builtin_amdgcn_s_setprio(1);
#pragma unroll
    for (int m = 0; m < MF; ++m)
#pragma unroll
      for (int n = 0; n < NF; ++n)
        acc[m][n] = __builtin_amdgcn_mfma_f32_16x16x32_bf16(af[m], bfr[n], acc[m][n], 0, 0, 0);
    __builtin_amdgcn_s_setprio(0);
    asm volatile("" ::: "memory");
    __builtin_amdgcn_s_barrier();
  }

#pragma unroll
  for (int m = 0; m < MF; ++m) {
    const int row = m0 + wm + m * 16 + lg * 4;
#pragma unroll
    for (int n = 0; n < NF; ++n) {
      const int col = n0 + wn + n * 16 + lr;
#pragma unroll
      for (int i = 0; i < 4; ++i) {
        float v = acc[m][n][i];
        size_t idx = (size_t)(row + i) * N + col;
        if constexpr (EPI == 0) {
          ((u16*)Cout)[idx] = f2bf(v + bias[col]);
        } else if constexpr (EPI == 2) {
          float cc = v + bias[col];
          float u = 0.7978845608f * (cc + 0.044715f * cc * cc * cc);
          float e = __expf(2.f * u);
          float th = 1.f - 2.f / (e + 1.f);
          ((u16*)Cout)[idx] = f2bf(0.5f * cc * (1.f + th));
        } else if constexpr (EPI == 4) {
          ((float*)Cout)[(size_t)blockIdx.z * M * N + idx] = v;
        } else {
          ((float*)Cout)[idx] = resid[idx] + gate[col] * (v + bias[col]);
        }
      }
    }
  }
}

// ---------------- combine 2 split-K partials: out = resid + gate*(p0+p1+bias) ----------------
__global__ __launch_bounds__(256)
void combine2(const float* __restrict__ part, const float* __restrict__ bias,
              const float* __restrict__ gate, const float* __restrict__ resid,
              float* __restrict__ out) {
  size_t idx = (size_t)blockIdx.x * 256 + threadIdx.x;   // over 2048*1024
  int col = (int)(idx & 1023);
  float v = part[idx] + part[(size_t)2048 * 1024 + idx] + bias[col];
  out[idx] = resid[idx] + gate[col] * v;
}

// ---------------- q/k: RMS norm + RoPE -> Q,K (h,pos,d) bf16 ----------------
// Q pre-scaled by (1/8)*log2(e): attention softmax runs in exp2 domain.
__global__ __launch_bounds__(256)
void qk_post(const u16* __restrict__ qkv_txt, const u16* __restrict__ qkv_img,
             const float* __restrict__ pe,
             const float* __restrict__ iq_s, const float* __restrict__ ik_s,
             const float* __restrict__ tq_s, const float* __restrict__ tk_s,
             u16* __restrict__ Q, u16* __restrict__ K) {
  const int d = threadIdx.x;                       // 0..63
  const int pos = blockIdx.x * 4 + threadIdx.y;    // 0..2303
  const int h = blockIdx.y;
  const u16* src; int r; const float *qs, *ks;
  if (pos < 256) { src = qkv_txt; r = pos; qs = tq_s; ks = tk_s; }
  else           { src = qkv_img; r = pos - 256; qs = iq_s; ks = ik_s; }
  float q = bf2f(src[(size_t)r * 3072 + h * 64 + d]);
  float k = bf2f(src[(size_t)r * 3072 + 1024 + h * 64 + d]);
  float qsq = q * q, ksq = k * k;
#pragma unroll
  for (int o = 32; o; o >>= 1) { qsq += __shfl_xor(qsq, o); ksq += __shfl_xor(ksq, o); }
  q *= rsqrtf(qsq * (1.f / 64.f) + 1e-6f) * qs[d];
  k *= rsqrtf(ksq * (1.f / 64.f) + 1e-6f) * ks[d];
  const int p = d >> 1, odd = d & 1;
  const float* pp = pe + (((size_t)pos * 32 + p) * 2 + odd) * 2;
  float qp = __shfl_xor(q, 1), kp = __shfl_xor(k, 1);
  float qe = odd ? qp : q, qo = odd ? q : qp;
  float ke = odd ? kp : k, ko = odd ? k : kp;
  float rq = pp[0] * qe + pp[1] * qo;
  float rk = pp[0] * ke + pp[1] * ko;
  size_t oidx = ((size_t)h * 2304 + pos) * 64 + d;
  Q[oidx] = f2bf(rq * 0.1803368801111204f);   // 0.125 * log2(e)
  K[oidx] = f2bf(rk);
}

// ---------------- V -> Vt (h, d, pos) bf16 ----------------
__global__ __launch_bounds__(512)
void v_transpose(const u16* __restrict__ qkv_txt, const u16* __restrict__ qkv_img,
                 u16* __restrict__ Vt) {
  __shared__ float tile[64][65];
  const int tx = threadIdx.x, ty = threadIdx.y;   // 64 x 8
  const int p0 = blockIdx.x * 64, h = blockIdx.y;
#pragma unroll
  for (int i = 0; i < 8; ++i) {
    int pos = p0 + ty + i * 8;
    const u16* src; int r;
    if (pos < 256) { src = qkv_txt; r = pos; } else { src = qkv_img; r = pos - 256; }
    tile[ty + i * 8][tx] = bf2f(src[(size_t)r * 3072 + 2048 + h * 64 + tx]);
  }
  __syncthreads();
#pragma unroll
  for (int i = 0; i < 8; ++i) {
    int d = ty + i * 8;
    Vt[((size_t)h * 64 + d) * 2304 + p0 + tx] = f2bf(tile[tx][d]);
  }
}

// ---------------- flash attention (split-KV, swapped QK^T, exp2 domain, defer-max) ----------------
// LDS 40 KB (4 blocks/CU via LDS when VGPR<=128); launch_bounds(256,3) so regalloc
// is NOT squeezed (r9: (256,4) forced 52 VGPR -> softmax state spilled, +45% VALU).
__global__ __launch_bounds__(256, 3)
void attn_kernel(const u16* __restrict__ Q, const u16* __restrict__ Kb,
                 const u16* __restrict__ Vt,
                 float* __restrict__ Opart, float* __restrict__ ml) {
  __shared__ u16 smK[2][64 * 64];
  __shared__ u16 smV[2][64 * 64];
  __shared__ u16 smP[4][16 * 64];
  const int t = threadIdx.x, w = t >> 6, l = t & 63;
  const int lr = l & 15, lg = l >> 4;
  const int qt = blockIdx.x, h = blockIdx.y, sp = blockIdx.z;
  const int j0 = sp * 18;
  const u16* Qp = Q + ((size_t)h * 2304 + qt * 64 + w * 16 + lr) * 64;
  const bf16x8 qf0 = *(const bf16x8*)(Qp + lg * 8);
  const bf16x8 qf1 = *(const bf16x8*)(Qp + 32 + lg * 8);
  const u16* Kbase = Kb + (size_t)h * 2304 * 64;
  const u16* Vbase = Vt + (size_t)h * 64 * 2304;
  f32x4 accO[4] = {};
  float mrun = -1e30f, lrun = 0.f;
  u16* myP = smP[w];

  const int c0 = w * 64 + l, c1 = c0 + 256;
  const int kr0 = c0 >> 3, ks0 = ((c0 & 7) ^ (kr0 & 7)) * 8;
  const int kr1 = c1 >> 3, ks1 = ((c1 & 7) ^ (kr1 & 7)) * 8;

  auto stage = [&](int j, int b) {
    const u16* gK = Kbase + (size_t)j * 64 * 64;
    GLDS16(gK + (size_t)kr0 * 64 + ks0, smK[b] + (w * 64) * 8);
    GLDS16(gK + (size_t)kr1 * 64 + ks1, smK[b] + (256 + w * 64) * 8);
    GLDS16(Vbase + (size_t)kr0 * 2304 + j * 64 + ks0, smV[b] + (w * 64) * 8);
    GLDS16(Vbase + (size_t)kr1 * 2304 + j * 64 + ks1, smV[b] + (256 + w * 64) * 8);
  };

  stage(j0, 0);
  for (int jj = 0; jj < 18; ++jj) {
    const int b = jj & 1;
    if (jj < 17) {
      stage(j0 + jj + 1, b ^ 1);
      asm volatile("s_waitcnt vmcnt(4)" ::: "memory");
    } else {
      asm volatile("s_waitcnt vmcnt(0)" ::: "memory");
    }
    __builtin_amdgcn_s_barrier();
    asm volatile("" ::: "memory");

    // S^T = K * Q^T (log2 domain): sf[n][i] = S[k = n*16+lg*4+i][q = lr]
    f32x4 sf[4];
    __builtin_amdgcn_s_setprio(1);
#pragma unroll
    for (int n = 0; n < 4; ++n) {
      const int row = n * 16 + lr, sw = row & 7;
      bf16x8 kf0 = *(const bf16x8*)(smK[b] + row * 64 + ((lg ^ sw) << 3));
      bf16x8 kf1 = *(const bf16x8*)(smK[b] + row * 64 + (((lg + 4) ^ sw) << 3));
      f32x4 z = {};
      z = __builtin_amdgcn_mfma_f32_16x16x32_bf16(kf0, qf0, z, 0, 0, 0);
      z = __builtin_amdgcn_mfma_f32_16x16x32_bf16(kf1, qf1, z, 0, 0, 0);
      sf[n] = z;
    }
    __builtin_amdgcn_s_setprio(0);

    // row max (q = lr): in-register tree + 2 shfl across lg groups
    float t0 = fmaxf(fmaxf(sf[0][0], sf[0][1]), fmaxf(sf[0][2], sf[0][3]));
    float t1 = fmaxf(fmaxf(sf[1][0], sf[1][1]), fmaxf(sf[1][2], sf[1][3]));
    float t2 = fmaxf(fmaxf(sf[2][0], sf[2][1]), fmaxf(sf[2][2], sf[2][3]));
    float t3 = fmaxf(fmaxf(sf[3][0], sf[3][1]), fmaxf(sf[3][2], sf[3][3]));
    float mx = fmaxf(fmaxf(t0, t1), fmaxf(t2, t3));
    mx = fmaxf(mx, __shfl_xor(mx, 16));
    mx = fmaxf(mx, __shfl_xor(mx, 32));

    // defer-max (T13): only rescale when some row grows by > 8 (log2 units).
    // P is then bounded by 2^8 = 256 — fine in f32 accum / bf16 P.
    if (!__all(mx <= mrun + 8.f)) {
      float mnew = fmaxf(mrun, mx);
      float corr = exp2f(mrun - mnew);
      mrun = mnew;
      lrun *= corr;
      float cb[4];
#pragma unroll
      for (int i = 0; i < 4; ++i) cb[i] = __shfl(corr, lg * 4 + i);
#pragma unroll
      for (int nd = 0; nd < 4; ++nd)
#pragma unroll
        for (int i = 0; i < 4; ++i) accO[nd][i] *= cb[i];
    }

    float p[4][4];
#pragma unroll
    for (int n = 0; n < 4; ++n) {
      p[n][0] = exp2f(sf[n][0] - mrun);
      p[n][1] = exp2f(sf[n][1] - mrun);
      p[n][2] = exp2f(sf[n][2] - mrun);
      p[n][3] = exp2f(sf[n][3] - mrun);
    }
    float s0 = (p[0][0] + p[0][1]) + (p[0][2] + p[0][3]);
    float s1 = (p[1][0] + p[1][1]) + (p[1][2] + p[1][3]);
    float s2 = (p[2][0] + p[2][1]) + (p[2][2] + p[2][3]);
    float s3 = (p[3][0] + p[3][1]) + (p[3][2] + p[3][3]);
    float rs = (s0 + s1) + (s2 + s3);
    rs += __shfl_xor(rs, 16);
    rs += __shfl_xor(rs, 32);
    lrun += rs;

    // P store into swizzled 16x64 tile: chunk' = chunk ^ (lr&7); b32 pairs.
#pragma unroll
    for (int n = 0; n < 4; ++n) {
      const int cA = (2 * n + (lg >> 1)) ^ (lr & 7);
      u16* base = myP + lr * 64 + cA * 8 + (lg & 1) * 4;
      *(unsigned*)(base)     = cvt_pk_bf16(p[n][0], p[n][1]);
      *(unsigned*)(base + 2) = cvt_pk_bf16(p[n][2], p[n][3]);
    }

    // PV: A-frag = P[q=lr][k = c*32+lg*8 ..+8] -> chunk 4c+lg, swizzled ^(lr&7)
    __builtin_amdgcn_s_setprio(1);
#pragma unroll
    for (int c = 0; c < 2; ++c) {
      bf16x8 pf = *(const bf16x8*)(myP + lr * 64 + (((4 * c + lg) ^ (lr & 7)) << 3));
#pragma unroll
      for (int nd = 0; nd < 4; ++nd) {
        const int row = nd * 16 + lr, sw = row & 7;
        bf16x8 vf = *(const bf16x8*)(smV[b] + row * 64 + (((c * 4 + lg) ^ sw) << 3));
        accO[nd] = __builtin_amdgcn_mfma_f32_16x16x32_bf16(pf, vf, accO[nd], 0, 0, 0);
      }
    }
    __builtin_amdgcn_s_setprio(0);
    asm volatile("" ::: "memory");
    __builtin_amdgcn_s_barrier();
  }

  float* Op = Opart + (((size_t)(sp * 16 + h) * 2304) + qt * 64) * 64;
#pragma unroll
  for (int nd = 0; nd < 4; ++nd)
#pragma unroll
    for (int i = 0; i < 4; ++i)
      Op[(size_t)(w * 16 + lg * 4 + i) * 64 + nd * 16 + lr] = accO[nd][i];
  if (lg == 0) {
    size_t mi = ((size_t)(sp * 16 + h) * 2304 + qt * 64 + w * 16 + lr) * 2;
    ml[mi] = mrun;
    ml[mi + 1] = lrun;
  }
}

// ---------------- combine split-KV partials -> out (pos, h*64+d) bf16 ----------------
__global__ __launch_bounds__(256)
void attn_combine(const float* __restrict__ Opart, const float* __restrict__ ml,
                  u16* __restrict__ outb) {
  int idx = blockIdx.x * 256 + threadIdx.x;       // over 2304*1024
  int q = idx >> 10, c = idx & 1023;
  int h = c >> 6, d = c & 63;
  size_t i0 = (size_t)h * 2304 + q;
  size_t i1 = (size_t)(16 + h) * 2304 + q;
  float m0 = ml[i0 * 2], l0 = ml[i0 * 2 + 1];
  float m1 = ml[i1 * 2], l1 = ml[i1 * 2 + 1];
  float M = fmaxf(m0, m1);
  float w0 = exp2f(m0 - M), w1 = exp2f(m1 - M);
  float a0 = Opart[i0 * 64 + d], a1 = Opart[i1 * 64 + d];
  float num = w0 * a0 + w1 * a1;
  float den = w0 * l0 + w1 * l1;
  outb[(size_t)q * 1024 + c] = f2bf(num / den);
}

// ---------------- host ----------------
extern "C" void kernel_launch(void* const* d_in, const int* in_sizes, int n_in,
                              void* d_out, int out_size, void* d_ws, size_t ws_size,
                              hipStream_t stream) {
  const float* img         = (const float*)d_in[0];
  const float* txt         = (const float*)d_in[1];
  const float* pe          = (const float*)d_in[2];
  const float* vec         = (const float*)d_in[3];
  const float* img_mod_w   = (const float*)d_in[4];
  const float* img_mod_b   = (const float*)d_in[5];
  const float* txt_mod_w   = (const float*)d_in[6];
  const float* txt_mod_b   = (const float*)d_in[7];
  const float* img_qkv_w   = (const float*)d_in[8];
  const float* img_qkv_b   = (const float*)d_in[9];
  const float* img_q_scale = (const float*)d_in[10];
  const float* img_k_scale = (const float*)d_in[11];
  const float* img_proj_w  = (const float*)d_in[12];
  const float* img_proj_b  = (const float*)d_in[13];
  const float* txt_qkv_w   = (const float*)d_in[14];
  const float* txt_qkv_b   = (const float*)d_in[15];
  const float* txt_q_scale = (const float*)d_in[16];
  const float* txt_k_scale = (const float*)d_in[17];
  const float* mlp_w1      = (const float*)d_in[18];
  const float* mlp_b1      = (const float*)d_in[19];
  const float* mlp_w2      = (const float*)d_in[20];
  const float* mlp_b2      = (const float*)d_in[21];
  (void)in_sizes; (void)n_in; (void)out_size; (void)ws_size;

  char* ws = (char*)d_ws;
  size_t off = 0;
  auto alloc = [&](size_t bytes) -> void* {
    void* p = ws + off;
    off += (bytes + 255) & ~(size_t)255;
    return p;
  };
  float* sv     = (float*)alloc(1024 * 4);
  float* mod    = (float*)alloc(8192 * 4);
  // --- aliased region (18,874,368 B): {qkv_img, qkv_txt, img_m, txt_m}
  //     == Opart (attn partials) == pml2 (mlp2 split-K partials)
  u16* qkv_img  = (u16*)alloc((size_t)2048 * 3072 * 2);
  u16* qkv_txt  = (u16*)alloc((size_t)256 * 3072 * 2);
  u16* img_m    = (u16*)alloc((size_t)2048 * 1024 * 2);
  u16* txt_m    = (u16*)alloc((size_t)256 * 1024 * 2);
  float* Opart  = (float*)qkv_img;
  float* pml2   = (float*)qkv_img;
  float* mlbuf  = (float*)alloc((size_t)2 * 16 * 2304 * 2 * 4);
  u16* wt_iqkv  = (u16*)alloc((size_t)3072 * 1024 * 2);
  u16* wt_tqkv  = (u16*)alloc((size_t)3072 * 1024 * 2);
  u16* wt_proj  = (u16*)alloc((size_t)1024 * 1024 * 2);
  u16* wt_m1    = (u16*)alloc((size_t)4096 * 1024 * 2);
  u16* wt_m2    = (u16*)alloc((size_t)1024 * 4096 * 2);
  u16* Qb       = (u16*)alloc((size_t)16 * 2304 * 64 * 2);
  u16* Kb       = (u16*)alloc((size_t)16 * 2304 * 64 * 2);
  u16* Vtb      = (u16*)alloc((size_t)16 * 64 * 2304 * 2);
  u16* attnb    = (u16*)alloc((size_t)2304 * 1024 * 2);
  float* img2   = (float*)alloc((size_t)2048 * 1024 * 4);
  u16* h_in     = (u16*)alloc((size_t)2048 * 1024 * 2);
  u16* h1       = (u16*)alloc((size_t)2048 * 4096 * 2);

  wconv_all<<<15360, dim3(32, 8), 0, stream>>>(img_qkv_w, txt_qkv_w, img_proj_w, mlp_w1, mlp_w2,
                                               wt_iqkv, wt_tqkv, wt_proj, wt_m1, wt_m2);

  silu_kernel<<<4, 256, 0, stream>>>(vec, sv);
  modinit<<<32, 256, 0, stream>>>(img_mod_b, txt_mod_b, mod);
  modgemv<<<dim3(32, 8), 256, 0, stream>>>(sv, img_mod_w, txt_mod_w, mod);

  ln_mod2<<<2304, 256, 0, stream>>>(img, txt, mod, img_m, txt_m);

  gemm_bt<0, 128, 128><<<dim3(16, 24), 256, 0, stream>>>(img_m, wt_iqkv, 2048, 3072, 1024, 1024,
                                                         img_qkv_b, nullptr, nullptr, qkv_img);
  gemm_bt<0, 128, 128><<<dim3(2, 24), 256, 0, stream>>>(txt_m, wt_tqkv, 256, 3072, 1024, 1024,
                                                        txt_qkv_b, nullptr, nullptr, qkv_txt);

  qk_post<<<dim3(576, 16), dim3(64, 4), 0, stream>>>(qkv_txt, qkv_img, pe,
                                                     img_q_scale, img_k_scale,
                                                     txt_q_scale, txt_k_scale, Qb, Kb);
  v_transpose<<<dim3(36, 16), dim3(64, 8), 0, stream>>>(qkv_txt, qkv_img, Vtb);

  // qkv_img/qkv_txt/img_m/txt_m are dead past here; Opart aliases them.
  attn_kernel<<<dim3(36, 16, 2), 256, 0, stream>>>(Qb, Kb, Vtb, Opart, mlbuf);
  attn_combine<<<9216, 256, 0, stream>>>(Opart, mlbuf, attnb);

  gemm_bt<1, 64, 64><<<dim3(32, 16), 256, 0, stream>>>(attnb + (size_t)256 * 1024, wt_proj,
                                                       2048, 1024, 1024, 1024,
                                                       img_proj_b, mod + 2048, img, img2);
  ln_mod2<<<2048, 256, 0, stream>>>(img2, nullptr, mod + 3072, h_in, nullptr);
  gemm_bt<2, 128, 128><<<dim3(16, 32), 256, 0, stream>>>(h_in, wt_m1, 2048, 4096, 1024, 1024,
                                                         mlp_b1, nullptr, nullptr, h1);
  gemm_bt<4, 64, 64><<<dim3(32, 16, 2), 256, 0, stream>>>(h1, wt_m2, 2048, 1024, 4096, 2048,
                                                          nullptr, nullptr, nullptr, pml2);
  combine2<<<8192, 256, 0, stream>>>(pml2, mlp_b2, mod + 5120, img2, (float*)d_out);
}